// Round 11
// baseline (398.963 us; speedup 1.0000x reference)
//
#include <hip/hip_runtime.h>
#include <stdint.h>

#define B_ 8
#define L_ 4096
#define D_ 1024
#define M_ (B_*L_)        // 32768 rows
#define CHUNKS 128
#define TCH (L_/CHUNKS)   // 32

typedef float f32x4 __attribute__((ext_vector_type(4)));
typedef float f32x2 __attribute__((ext_vector_type(2)));
typedef float f32x16 __attribute__((ext_vector_type(16)));
typedef short short8 __attribute__((ext_vector_type(8)));
typedef unsigned short ushort4v __attribute__((ext_vector_type(4)));

static __device__ __forceinline__ unsigned short f2bf(float f) {
  union { float f; unsigned u; } v; v.f = f;
  unsigned r = v.u + 0x7FFFu + ((v.u >> 16) & 1u);   // round-to-nearest-even
  return (unsigned short)(r >> 16);
}
static __device__ __forceinline__ float bf2f(unsigned short u) {
  union { unsigned u; float f; } v; v.u = ((unsigned)u) << 16; return v.f;
}

#define GLOAD16(g, l) \
  __builtin_amdgcn_global_load_lds((__attribute__((address_space(1))) const void*)(g), \
                                   (__attribute__((address_space(3))) void*)(l), 16, 0, 0)

// ---------------------------------------------------------------------------
// fp32 -> bf16 converts
// ---------------------------------------------------------------------------
__global__ __launch_bounds__(256)
void cvt_bf16(const float* __restrict__ src, unsigned short* __restrict__ dst, int n8)
{
  int gid = blockIdx.x * 256 + threadIdx.x;
  if (gid >= n8) return;
  const f32x4* s = (const f32x4*)(src + (size_t)gid * 8);
  f32x4 v0 = s[0], v1 = s[1];
  union { short8 v; unsigned short u[8]; } w;
  w.u[0] = f2bf(v0[0]); w.u[1] = f2bf(v0[1]); w.u[2] = f2bf(v0[2]); w.u[3] = f2bf(v0[3]);
  w.u[4] = f2bf(v1[0]); w.u[5] = f2bf(v1[1]); w.u[6] = f2bf(v1[2]); w.u[7] = f2bf(v1[3]);
  *(short8*)(dst + (size_t)gid * 8) = w.v;
}

__global__ __launch_bounds__(256)
void cvt_w3(const float* __restrict__ w0, const float* __restrict__ w1,
            const float* __restrict__ w2, unsigned short* __restrict__ dst)
{
  const int per = (D_ * D_) / 8 / 256;
  int m = blockIdx.x / per;
  int gid = (blockIdx.x % per) * 256 + threadIdx.x;
  const float* src = (m == 0) ? w0 : (m == 1) ? w1 : w2;
  const f32x4* s = (const f32x4*)(src + (size_t)gid * 8);
  f32x4 v0 = s[0], v1 = s[1];
  union { short8 v; unsigned short u[8]; } w;
  w.u[0] = f2bf(v0[0]); w.u[1] = f2bf(v0[1]); w.u[2] = f2bf(v0[2]); w.u[3] = f2bf(v0[3]);
  w.u[4] = f2bf(v1[0]); w.u[5] = f2bf(v1[1]); w.u[6] = f2bf(v1[2]); w.u[7] = f2bf(v1[3]);
  *(short8*)(dst + (size_t)m * D_ * D_ + (size_t)gid * 8) = w.v;
}

// ---------------------------------------------------------------------------
// 256x256 8-wave GEMM. Ring-5 chunk pipeline (r10 skeleton) with:
//  * 32x32x16 MFMA (16 instr/chunk/wave vs 32; pipe ceiling 2495 vs 2176 TF)
//  * ds_reads for A-tile i+1 issued BEFORE tile i's MFMA cluster so the LDS
//    pipe services reads underneath the matrix pipe (the 36% plateau across
//    r8/r9/r10 was the burst-read -> compute serialization, not prefetch depth)
// chunk = 32 K-cols (16 KB); A ring-5 (80KB) + B ring-5 (80KB @ +81920).
// Per chunk: 1 barrier, 1 counted vmcnt(12) (drains exactly chunk c+1).
// MODE 0: stacked gates Bw=[W_f;W_i]; writes rem=lin*sig(zf+b), t=tanh(zi+b)
// MODE 1: y = h*W_o^T + b_o fp32.
// A-locality dispatch: 32 co-resident blocks/XCD = {GBM bm} x {all bn}.
// ---------------------------------------------------------------------------
template<int MODE>
__global__ __launch_bounds__(512, 2)
void gemm256(const unsigned short* __restrict__ A,
             const unsigned short* __restrict__ Bw,
             const float* __restrict__ bias0,
             const float* __restrict__ bias1,
             unsigned short* __restrict__ ob0,   // rem (MODE 0)
             unsigned short* __restrict__ ob1,   // t   (MODE 0)
             float* __restrict__ of)             // y   (MODE 1)
{
  __shared__ unsigned short lds[81920];   // 160 KB: A slots 0..4 | B slots at +81920
  char* ldsb = (char*)lds;

  const int tid  = threadIdx.x;
  const int lane = tid & 63;
  const int wid  = tid >> 6;
  const int wm   = wid >> 2;          // 0..1
  const int wn   = wid & 3;           // 0..3
  const int r32  = lane & 31;         // row within a 32-tile
  const int ks2  = lane >> 5;         // k-slot (0..1) for 32x32x16 frags

  constexpr int NBN = (MODE == 0) ? 8 : 4;
  constexpr int GBM = 32 / NBN;
  const int xcd   = blockIdx.x & 7;
  const int slot  = blockIdx.x >> 3;
  const int local = slot & 31;
  const int wrnd  = slot >> 5;
  const int bm = (xcd * 16 + wrnd * GBM + (local & (GBM - 1))) * 256;
  const int bn = (local / GBM) * 256;

  const int r0  = tid >> 2;
  const int scl = ((tid & 3) ^ ((r0 >> 1) & 3)) << 4;   // pre-swizzled source slot
  const char* pA = (const char*)A  + (size_t)(bm + r0) * 2048 + scl;
  const char* pB = (const char*)Bw + (size_t)(bn + r0) * 2048 + scl;
  const int dst16 = tid * 16;

  f32x16 acc[4][2] = {};          // 4 row-tiles x 2 col-tiles of 32x32
  short8 bq00, bq01, bq10, bq11;  // B frags [j][kh]
  short8 aqA0, aqA1, aqB0, aqB1;  // double-buffered A frags [kh]

  auto stgA = [&](int c, int sl) {
    const char* s = pA + c * 64;
    char* d = ldsb + sl * 16384 + dst16;
    GLOAD16(s,                      d);
    GLOAD16(s + (size_t)128 * 2048, d + 8192);
  };
  auto stgB = [&](int c, int sl) {
    const char* s = pB + c * 64;
    char* d = ldsb + 81920 + sl * 16384 + dst16;
    GLOAD16(s,                      d);
    GLOAD16(s + (size_t)128 * 2048, d + 8192);
  };

  // 32x32x16 A/B fragment: lane reads row (base+r32), k = 8*ks2 + kh*... :
  // logical 16B slot = kh*2 + ks2, physical = slot ^ ((row>>1)&3)
  auto ldA = [&](const char* LA, int i, short8& d0, short8& d1) {
    int row = wm * 128 + i * 32 + r32;
    const char* rb = LA + row * 64;
    int x = (row >> 1) & 3;
    d0 = *(const short8*)(rb + (((ks2)     ^ x) << 4));   // kh=0
    d1 = *(const short8*)(rb + (((2 + ks2) ^ x) << 4));   // kh=1
  };
  auto ldB = [&](const char* LB) {
    int rowb = wn * 64 + r32;
    const char* rb0 = LB + rowb * 64;
    const char* rb1 = LB + (rowb + 32) * 64;
    int x0 = (rowb >> 1) & 3;
    int x1 = ((rowb + 32) >> 1) & 3;
    bq00 = *(const short8*)(rb0 + (((ks2)     ^ x0) << 4));
    bq01 = *(const short8*)(rb0 + (((2 + ks2) ^ x0) << 4));
    bq10 = *(const short8*)(rb1 + (((ks2)     ^ x1) << 4));
    bq11 = *(const short8*)(rb1 + (((2 + ks2) ^ x1) << 4));
  };

#define MFMA4(i, a0, a1)                                                      \
  {                                                                           \
    __builtin_amdgcn_s_setprio(1);                                            \
    acc[i][0] = __builtin_amdgcn_mfma_f32_32x32x16_bf16(a0, bq00, acc[i][0], 0, 0, 0); \
    acc[i][1] = __builtin_amdgcn_mfma_f32_32x32x16_bf16(a0, bq10, acc[i][1], 0, 0, 0); \
    acc[i][0] = __builtin_amdgcn_mfma_f32_32x32x16_bf16(a1, bq01, acc[i][0], 0, 0, 0); \
    acc[i][1] = __builtin_amdgcn_mfma_f32_32x32x16_bf16(a1, bq11, acc[i][1], 0, 0, 0); \
    __builtin_amdgcn_s_setprio(0);                                            \
  }

#define BAR __builtin_amdgcn_s_barrier()
#define WAITV(N) asm volatile("s_waitcnt vmcnt(" #N ")" ::: "memory")
// chunk c: read slot SL; stage chunk c+4 -> slot SG; wait WN drains chunk c+1.
// A-tile i+1 reads are issued BEFORE tile i's MFMA cluster (LDS || MFMA).
#define DO_CH(c, SL, SG, STG, WN)                                             \
  {                                                                           \
    const char* LA = ldsb + (SL) * 16384;                                     \
    const char* LB = ldsb + 81920 + (SL) * 16384;                             \
    ldB(LB);                                                                  \
    ldA(LA, 0, aqA0, aqA1);                                                   \
    if (STG) stgA((c) + 4, (SG));                                             \
    ldA(LA, 1, aqB0, aqB1);                                                   \
    MFMA4(0, aqA0, aqA1);                                                     \
    ldA(LA, 2, aqA0, aqA1);                                                   \
    MFMA4(1, aqB0, aqB1);                                                     \
    if (STG) stgB((c) + 4, (SG));                                             \
    ldA(LA, 3, aqB0, aqB1);                                                   \
    MFMA4(2, aqA0, aqA1);                                                     \
    MFMA4(3, aqB0, aqB1);                                                     \
    WAITV(WN);                                                                \
    BAR;                                                                      \
  }

  // prologue: chunks 0..3 (A,B interleaved; oldest = chunk 0) -> 16 loads
  stgA(0, 0); stgB(0, 0);
  stgA(1, 1); stgB(1, 1);
  stgA(2, 2); stgB(2, 2);
  stgA(3, 3); stgB(3, 3);
  WAITV(12);                          // chunk 0 resident
  BAR;

  DO_CH( 0, 0, 4, true, 12);
  DO_CH( 1, 1, 0, true, 12);
  DO_CH( 2, 2, 1, true, 12);
  DO_CH( 3, 3, 2, true, 12);
  DO_CH( 4, 4, 3, true, 12);
  DO_CH( 5, 0, 4, true, 12);
  DO_CH( 6, 1, 0, true, 12);
  DO_CH( 7, 2, 1, true, 12);
  DO_CH( 8, 3, 2, true, 12);
  DO_CH( 9, 4, 3, true, 12);
  DO_CH(10, 0, 4, true, 12);
  DO_CH(11, 1, 0, true, 12);
  DO_CH(12, 2, 1, true, 12);
  DO_CH(13, 3, 2, true, 12);
  DO_CH(14, 4, 3, true, 12);
  DO_CH(15, 0, 4, true, 12);
  DO_CH(16, 1, 0, true, 12);
  DO_CH(17, 2, 1, true, 12);
  DO_CH(18, 3, 2, true, 12);
  DO_CH(19, 4, 3, true, 12);
  DO_CH(20, 0, 4, true, 12);
  DO_CH(21, 1, 0, true, 12);
  DO_CH(22, 2, 1, true, 12);
  DO_CH(23, 3, 2, true, 12);
  DO_CH(24, 4, 3, true, 12);
  DO_CH(25, 0, 4, true, 12);
  DO_CH(26, 1, 0, true, 12);
  DO_CH(27, 2, 1, true, 12);   // stages chunk 31 (last)
  DO_CH(28, 3, 0, false, 8);
  DO_CH(29, 4, 0, false, 4);
  DO_CH(30, 0, 0, false, 0);
  {
    const char* LA = ldsb + 1 * 16384;
    const char* LB = ldsb + 81920 + 1 * 16384;
    ldB(LB);
    ldA(LA, 0, aqA0, aqA1);
    ldA(LA, 1, aqB0, aqB1);
    MFMA4(0, aqA0, aqA1);
    ldA(LA, 2, aqA0, aqA1);
    MFMA4(1, aqB0, aqB1);
    ldA(LA, 3, aqB0, aqB1);
    MFMA4(2, aqA0, aqA1);
    MFMA4(3, aqB0, aqB1);
  }
#undef DO_CH
#undef MFMA4
#undef WAITV
#undef BAR

  // epilogue: 32x32 C/D mapping col=lane&31, row=(reg&3)+8*(reg>>2)+4*(lane>>5)
  if constexpr (MODE == 0) {
    const int plane = bn >> 10;                 // 0: rem, 1: tanh
    const int cb    = bn & 1023;
    unsigned short* ob = plane ? ob1 : ob0;
    const float* bs    = plane ? bias1 : bias0;
    #pragma unroll
    for (int i = 0; i < 4; ++i) {
      int rbase = bm + wm * 128 + i * 32 + 4 * ks2;
      #pragma unroll
      for (int j = 0; j < 2; ++j) {
        int col = cb + wn * 64 + j * 32 + r32;
        float bj  = bs[col];
        float lin = (float)col * (1.0f / 1023.0f);
        #pragma unroll
        for (int reg = 0; reg < 16; ++reg) {
          int row = rbase + (reg & 3) + 8 * (reg >> 2);
          float z = acc[i][j][reg] + bj;
          float v;
          if (plane == 0) {
            v = lin / (1.0f + __expf(-z));             // rem (small, bf16-safe)
          } else {
            float e2 = __expf(2.0f * z);
            v = 1.0f - 2.0f / (e2 + 1.0f);             // tanh
          }
          ob[(size_t)row * D_ + col] = f2bf(v);
        }
      }
    }
  } else {
    #pragma unroll
    for (int i = 0; i < 4; ++i) {
      int rbase = bm + wm * 128 + i * 32 + 4 * ks2;
      #pragma unroll
      for (int j = 0; j < 2; ++j) {
        int col = bn + wn * 64 + j * 32 + r32;
        float bj = bias0[col];
        #pragma unroll
        for (int reg = 0; reg < 16; ++reg) {
          int row = rbase + (reg & 3) + 8 * (reg >> 2);
          of[(size_t)row * D_ + col] = acc[i][j][reg] + bj;
        }
      }
    }
  }
}

// ---------------------------------------------------------------------------
// Chunked parallel scan over precomputed (rem, t), 4 channels/thread.
// f = 1 - rem (fp32);  h_t = f*h_{t-1} + t*rem
// ---------------------------------------------------------------------------
__global__ __launch_bounds__(256)
void scan_partial_b(const unsigned short* __restrict__ rb,
                    const unsigned short* __restrict__ tb,
                    float* __restrict__ Ag, float* __restrict__ Ug)
{
  int blk = blockIdx.x;
  int b = blk >> 7, c = blk & (CHUNKS - 1);
  int e = threadIdx.x << 2;
  size_t base = ((size_t)b * L_ + (size_t)c * TCH) * D_ + e;
  f32x4 a = {1.f,1.f,1.f,1.f}, u = {0.f,0.f,0.f,0.f};
  for (int t = 0; t < TCH; ++t) {
    ushort4v r4 = *(const ushort4v*)(rb + base + (size_t)t * D_);
    ushort4v t4 = *(const ushort4v*)(tb + base + (size_t)t * D_);
    #pragma unroll
    for (int j = 0; j < 4; ++j) {
      float rem = bf2f(r4[j]);
      float f   = 1.0f - rem;
      float inp = bf2f(t4[j]) * rem;
      u[j] = fmaf(f, u[j], inp);
      a[j] *= f;
    }
  }
  size_t o = (size_t)(b * CHUNKS + c) * D_ + e;
  *(f32x4*)(Ag + o) = a;
  *(f32x4*)(Ug + o) = u;
}

__global__ __launch_bounds__(256)
void scan_carry(const float* __restrict__ Ag, const float* __restrict__ Ug,
                const float* __restrict__ hidden, float* __restrict__ Hin)
{
  int gid = blockIdx.x * 256 + threadIdx.x;  // B_*D_/4 threads
  int b = gid >> 8;
  int e = (gid & 255) << 2;
  f32x4 h = *(const f32x4*)(hidden + (size_t)b * D_ + e);
  for (int c = 0; c < CHUNKS; ++c) {
    size_t o = (size_t)(b * CHUNKS + c) * D_ + e;
    *(f32x4*)(Hin + o) = h;
    f32x4 A = *(const f32x4*)(Ag + o);
    f32x4 U = *(const f32x4*)(Ug + o);
    h = A * h + U;
  }
}

__global__ __launch_bounds__(256)
void scan_apply_b(const unsigned short* __restrict__ rb,
                  const unsigned short* __restrict__ tb,
                  const float* __restrict__ Hin,
                  float* __restrict__ hout, unsigned short* __restrict__ hb)
{
  int blk = blockIdx.x;
  int b = blk >> 7, c = blk & (CHUNKS - 1);
  int e = threadIdx.x << 2;
  size_t base = ((size_t)b * L_ + (size_t)c * TCH) * D_ + e;
  f32x4 h = *(const f32x4*)(Hin + (size_t)(b * CHUNKS + c) * D_ + e);
  for (int t = 0; t < TCH; ++t) {
    size_t o = base + (size_t)t * D_;
    ushort4v r4 = *(const ushort4v*)(rb + o);
    ushort4v t4 = *(const ushort4v*)(tb + o);
    #pragma unroll
    for (int j = 0; j < 4; ++j) {
      float rem = bf2f(r4[j]);
      float f   = 1.0f - rem;
      float inp = bf2f(t4[j]) * rem;
      h[j] = fmaf(f, h[j], inp);
    }
    *(f32x4*)(hout + o) = h;
    ushort4v p;
    p[0] = f2bf(h[0]); p[1] = f2bf(h[1]); p[2] = f2bf(h[2]); p[3] = f2bf(h[3]);
    *(ushort4v*)(hb + o) = p;
  }
}

// ---------------------------------------------------------------------------
// Slow fallback (fp32 in) — only if ws too small (never expected).
// ---------------------------------------------------------------------------
template<int MODE>
__global__ __launch_bounds__(256, 2)
void gemm_slow(const float* __restrict__ A, const float* __restrict__ B0,
               const float* __restrict__ B1, const float* __restrict__ bias0,
               const float* __restrict__ bias1, float* __restrict__ out0,
               float* __restrict__ out1)
{
  constexpr int BK = 32;
  __shared__ unsigned short As[128 * BK];
  __shared__ unsigned short Bs0[128 * BK];
  __shared__ unsigned short Bs1[(MODE == 0) ? (128 * BK) : 8];

  const int tid = threadIdx.x, lane = tid & 63, wave = tid >> 6;
  const int wr = wave >> 1, wc = wave & 1;
  const int bm = blockIdx.x * 128, bn = blockIdx.y * 128;
  f32x4 acc0[4][4] = {};
  f32x4 acc1[(MODE == 0) ? 4 : 1][(MODE == 0) ? 4 : 1] = {};
  const int frow = lane & 15, kslot = lane >> 4;
  const int xs = kslot ^ (frow & 3);

  auto stage = [&](const float* src, unsigned short* dst) {
    #pragma unroll
    for (int p = 0; p < 4; ++p) {
      int g = p * 256 + tid;
      int row = g >> 3, kq = (g & 7) << 2;
      f32x4 v = *(const f32x4*)(src + (size_t)row * D_ + kq);
      ushort4v w;
      w[0] = f2bf(v[0]); w[1] = f2bf(v[1]); w[2] = f2bf(v[2]); w[3] = f2bf(v[3]);
      int byte = kq << 1, slot = byte >> 4, sub = byte & 15;
      int off = row * 64 + ((slot ^ (row & 3)) << 4) + sub;
      *(ushort4v*)((char*)dst + off) = w;
    }
  };

  for (int k0 = 0; k0 < D_; k0 += BK) {
    stage(A + (size_t)bm * D_ + k0, As);
    stage(B0 + (size_t)bn * D_ + k0, Bs0);
    if constexpr (MODE == 0) stage(B1 + (size_t)bn * D_ + k0, Bs1);
    __syncthreads();
    short8 af[4], bf0[4], bf1[4];
    #pragma unroll
    for (int i = 0; i < 4; ++i) {
      int ar = wr * 64 + i * 16 + frow;
      af[i] = *(const short8*)((const char*)As + ar * 64 + (xs << 4));
      int br = wc * 64 + i * 16 + frow;
      bf0[i] = *(const short8*)((const char*)Bs0 + br * 64 + (xs << 4));
      if constexpr (MODE == 0)
        bf1[i] = *(const short8*)((const char*)Bs1 + br * 64 + (xs << 4));
    }
    #pragma unroll
    for (int i = 0; i < 4; ++i)
      #pragma unroll
      for (int j = 0; j < 4; ++j) {
        acc0[i][j] = __builtin_amdgcn_mfma_f32_16x16x32_bf16(af[i], bf0[j], acc0[i][j], 0, 0, 0);
        if constexpr (MODE == 0)
          acc1[i][j] = __builtin_amdgcn_mfma_f32_16x16x32_bf16(af[i], bf1[j], acc1[i][j], 0, 0, 0);
      }
    __syncthreads();
  }
  #pragma unroll
  for (int i = 0; i < 4; ++i)
    #pragma unroll
    for (int j = 0; j < 4; ++j)
      #pragma unroll
      for (int r = 0; r < 4; ++r) {
        int row = bm + wr * 64 + i * 16 + (lane >> 4) * 4 + r;
        int col = bn + wc * 64 + j * 16 + (lane & 15);
        size_t idx = (size_t)row * D_ + col;
        if constexpr (MODE == 0) {
          float zf = acc0[i][j][r] + bias0[col];
          float linv = (float)col * (1.0f / 1023.0f);
          float rem = linv / (1.0f + __expf(-zf));
          float zi = acc1[i][j][r] + bias1[col];
          float e2 = __expf(2.0f * zi);
          float th = 1.0f - 2.0f / (e2 + 1.0f);
          out0[idx] = 1.0f - rem;
          out1[idx] = th * rem;
        } else {
          out0[idx] = acc0[i][j][r] + bias0[col];
        }
      }
}

__global__ __launch_bounds__(256)
void scan_partial_f(const float* __restrict__ p0, const float* __restrict__ p1,
                    float* __restrict__ Ag, float* __restrict__ Ug)
{
  int blk = blockIdx.x;
  int b = blk / (CHUNKS * 2);
  int c = (blk >> 1) & (CHUNKS - 1);
  int e = ((blk & 1) << 9) + threadIdx.x * 2;
  size_t base = ((size_t)b * L_ + (size_t)c * TCH) * D_ + e;
  f32x2 a = {1.0f, 1.0f}, u = {0.0f, 0.0f};
  for (int t = 0; t < TCH; ++t) {
    f32x2 f = *(const f32x2*)(p0 + base + (size_t)t * D_);
    f32x2 i = *(const f32x2*)(p1 + base + (size_t)t * D_);
    u = f * u + i;
    a = a * f;
  }
  size_t o = (size_t)(b * CHUNKS + c) * D_ + e;
  *(f32x2*)(Ag + o) = a;
  *(f32x2*)(Ug + o) = u;
}

__global__ __launch_bounds__(256)
void scan_apply_f(const float* __restrict__ p0, float* __restrict__ p1_io,
                  const float* __restrict__ Hin)
{
  int blk = blockIdx.x;
  int b = blk / (CHUNKS * 2);
  int c = (blk >> 1) & (CHUNKS - 1);
  int e = ((blk & 1) << 9) + threadIdx.x * 2;
  size_t base = ((size_t)b * L_ + (size_t)c * TCH) * D_ + e;
  f32x2 h = *(const f32x2*)(Hin + (size_t)(b * CHUNKS + c) * D_ + e);
  for (int t = 0; t < TCH; ++t) {
    size_t o = base + (size_t)t * D_;
    f32x2 f = *(const f32x2*)(p0 + o);
    f32x2 i = *(const f32x2*)(p1_io + o);
    h = f * h + i;
    *(f32x2*)(p1_io + o) = h;
  }
}

// ---------------------------------------------------------------------------
extern "C" void kernel_launch(void* const* d_in, const int* in_sizes, int n_in,
                              void* d_out, int out_size, void* d_ws, size_t ws_size,
                              hipStream_t stream)
{
  const float* x      = (const float*)d_in[0];
  const float* hidden = (const float*)d_in[1];
  const float* W_f    = (const float*)d_in[2];
  const float* b_f    = (const float*)d_in[3];
  const float* W_i    = (const float*)d_in[4];
  const float* b_i    = (const float*)d_in[5];
  const float* W_o    = (const float*)d_in[6];
  const float* b_o    = (const float*)d_in[7];

  float* y = (float*)d_out;
  float* h = y + (size_t)M_ * D_;

  const size_t xb_elems = (size_t)M_ * D_;
  const size_t w_elems  = (size_t)D_ * D_;
  const size_t agg      = (size_t)B_ * CHUNKS * D_;
  const size_t need = (xb_elems * 3 + 3 * w_elems) * 2 + agg * 3 * 4;

  if (ws_size >= need) {
    unsigned short* xb  = (unsigned short*)d_ws;       // bf16 x, later bf16 h
    unsigned short* wfb = xb + xb_elems;               // [W_f;W_i] stacked
    unsigned short* wib = wfb + w_elems;
    unsigned short* wob = wib + w_elems;
    unsigned short* rbv = wob + w_elems;               // bf16 rem
    unsigned short* tbv = rbv + xb_elems;              // bf16 tanh
    float* Ag  = (float*)(tbv + xb_elems);
    float* Ug  = Ag + agg;
    float* Hin = Ug + agg;

    cvt_bf16<<<(int)(xb_elems / 8 / 256), 256, 0, stream>>>(x, xb, (int)(xb_elems / 8));
    cvt_w3<<<3 * (int)(w_elems / 8 / 256), 256, 0, stream>>>(W_f, W_i, W_o, wfb);

    gemm256<0><<<1024, 512, 0, stream>>>(xb, wfb, b_f, b_i, rbv, tbv, nullptr);

    int pblocks = B_ * CHUNKS;               // 1024
    scan_partial_b<<<pblocks, 256, 0, stream>>>(rbv, tbv, Ag, Ug);
    scan_carry<<<(B_ * D_ / 4) / 256, 256, 0, stream>>>(Ag, Ug, hidden, Hin);
    scan_apply_b<<<pblocks, 256, 0, stream>>>(rbv, tbv, Hin, h, xb);

    gemm256<1><<<512, 512, 0, stream>>>(xb, wob, b_o, nullptr, nullptr, nullptr, y);
  } else {
    float* Ag  = (float*)d_ws;
    float* Ug  = Ag + agg;
    float* Hin = Ug + agg;
    dim3 gg(M_ / 128, D_ / 128);
    int pblocks = B_ * CHUNKS * 2;

    gemm_slow<0><<<gg, 256, 0, stream>>>(x, W_f, W_i, b_f, b_i, y, h);
    scan_partial_f<<<pblocks, 256, 0, stream>>>(y, h, Ag, Ug);
    scan_carry<<<(B_ * D_ / 4) / 256, 256, 0, stream>>>(Ag, Ug, hidden, Hin);
    scan_apply_f<<<pblocks, 256, 0, stream>>>(y, h, Hin);
    gemm_slow<1><<<gg, 256, 0, stream>>>(h, W_o, nullptr, b_o, nullptr, y, nullptr);
  }
}

// Round 12
// 398.687 us; speedup vs baseline: 1.0007x; 1.0007x over previous
//
#include <hip/hip_runtime.h>
#include <stdint.h>

#define B_ 8
#define L_ 4096
#define D_ 1024
#define M_ (B_*L_)        // 32768 rows
#define CHUNKS 128
#define TCH (L_/CHUNKS)   // 32

typedef float f32x4 __attribute__((ext_vector_type(4)));
typedef float f32x2 __attribute__((ext_vector_type(2)));
typedef short short8 __attribute__((ext_vector_type(8)));
typedef unsigned short ushort4v __attribute__((ext_vector_type(4)));

static __device__ __forceinline__ unsigned short f2bf(float f) {
  union { float f; unsigned u; } v; v.f = f;
  unsigned r = v.u + 0x7FFFu + ((v.u >> 16) & 1u);   // round-to-nearest-even
  return (unsigned short)(r >> 16);
}
static __device__ __forceinline__ float bf2f(unsigned short u) {
  union { unsigned u; float f; } v; v.u = ((unsigned)u) << 16; return v.f;
}

#define GLOAD16(g, l) \
  __builtin_amdgcn_global_load_lds((__attribute__((address_space(1))) const void*)(g), \
                                   (__attribute__((address_space(3))) void*)(l), 16, 0, 0)

// ---------------------------------------------------------------------------
// fp32 -> bf16 converts
// ---------------------------------------------------------------------------
__global__ __launch_bounds__(256)
void cvt_bf16(const float* __restrict__ src, unsigned short* __restrict__ dst, int n8)
{
  int gid = blockIdx.x * 256 + threadIdx.x;
  if (gid >= n8) return;
  const f32x4* s = (const f32x4*)(src + (size_t)gid * 8);
  f32x4 v0 = s[0], v1 = s[1];
  union { short8 v; unsigned short u[8]; } w;
  w.u[0] = f2bf(v0[0]); w.u[1] = f2bf(v0[1]); w.u[2] = f2bf(v0[2]); w.u[3] = f2bf(v0[3]);
  w.u[4] = f2bf(v1[0]); w.u[5] = f2bf(v1[1]); w.u[6] = f2bf(v1[2]); w.u[7] = f2bf(v1[3]);
  *(short8*)(dst + (size_t)gid * 8) = w.v;
}

__global__ __launch_bounds__(256)
void cvt_w3(const float* __restrict__ w0, const float* __restrict__ w1,
            const float* __restrict__ w2, unsigned short* __restrict__ dst)
{
  const int per = (D_ * D_) / 8 / 256;
  int m = blockIdx.x / per;
  int gid = (blockIdx.x % per) * 256 + threadIdx.x;
  const float* src = (m == 0) ? w0 : (m == 1) ? w1 : w2;
  const f32x4* s = (const f32x4*)(src + (size_t)gid * 8);
  f32x4 v0 = s[0], v1 = s[1];
  union { short8 v; unsigned short u[8]; } w;
  w.u[0] = f2bf(v0[0]); w.u[1] = f2bf(v0[1]); w.u[2] = f2bf(v0[2]); w.u[3] = f2bf(v0[3]);
  w.u[4] = f2bf(v1[0]); w.u[5] = f2bf(v1[1]); w.u[6] = f2bf(v1[2]); w.u[7] = f2bf(v1[3]);
  *(short8*)(dst + (size_t)m * D_ * D_ + (size_t)gid * 8) = w.v;
}

// ---------------------------------------------------------------------------
// 256x256 8-wave GEMM. Ring-5 chunk pipeline + REGISTER DOUBLE-BUFFERED
// fragments: iteration c = [vmcnt(8); BAR; ds_read chunk c+1 -> frag[P^1];
// stage chunk c+4; 32 MFMA on frag[P]].  The MFMA cluster has no dependency
// on the just-issued reads, so the LDS pipe services them UNDER the ~1242-cy
// MFMA window (r8-r11 plateau at 36% = read-service serialized with MFMA).
// 16x16x32 MFMA, r10's conflict-free fragment pattern (r11's 32x32 pattern
// had rows r/r+8 same-bank 4-way conflicts).
// Hazards: WAR slot(c-1) <- stage(c+4): safe, BAR(c) passes only after every
// wave's MFMA(c-1) whose lgkm wait retired dsr(c-1). RAW chunk c+1: vmcnt(8)
// +BAR. chunk = 32 K-cols (16KB); A ring-5 (80KB) + B ring-5 (80KB @+81920).
// MODE 0: stacked gates Bw=[W_f;W_i]; writes rem=lin*sig(zf+b), t=tanh(zi+b)
// MODE 1: y = h*W_o^T + b_o fp32.
// A-locality dispatch: 32 co-resident blocks/XCD = {GBM bm} x {all bn}.
// ---------------------------------------------------------------------------
template<int MODE>
__global__ __launch_bounds__(512, 2)
void gemm256(const unsigned short* __restrict__ A,
             const unsigned short* __restrict__ Bw,
             const float* __restrict__ bias0,
             const float* __restrict__ bias1,
             unsigned short* __restrict__ ob0,   // rem (MODE 0)
             unsigned short* __restrict__ ob1,   // t   (MODE 0)
             float* __restrict__ of)             // y   (MODE 1)
{
  __shared__ unsigned short lds[81920];   // 160 KB: A slots 0..4 | B slots at +81920
  char* ldsb = (char*)lds;

  const int tid  = threadIdx.x;
  const int lane = tid & 63;
  const int wid  = tid >> 6;
  const int wm   = wid >> 2;          // 0..1
  const int wn   = wid & 3;           // 0..3
  const int frow = lane & 15, ks = lane >> 4;
  const int xsw  = (ks ^ ((frow >> 1) & 3)) << 4;

  constexpr int NBN = (MODE == 0) ? 8 : 4;
  constexpr int GBM = 32 / NBN;
  const int xcd   = blockIdx.x & 7;
  const int slot  = blockIdx.x >> 3;
  const int local = slot & 31;
  const int wrnd  = slot >> 5;
  const int bm = (xcd * 16 + wrnd * GBM + (local & (GBM - 1))) * 256;
  const int bn = (local / GBM) * 256;

  const int r0  = tid >> 2;
  const int scl = ((tid & 3) ^ ((r0 >> 1) & 3)) << 4;   // pre-swizzled source slot
  const char* pA = (const char*)A  + (size_t)(bm + r0) * 2048 + scl;
  const char* pB = (const char*)Bw + (size_t)(bn + r0) * 2048 + scl;
  const int dst16 = tid * 16;

  f32x4 acc[8][4] = {};
  short8 fA[2][8];    // [parity][ih*4+i] — literal indices only (rule 20)
  short8 fB[2][4];

  auto stgA = [&](int c, int sl) {
    const char* s = pA + c * 64;
    char* d = ldsb + sl * 16384 + dst16;
    GLOAD16(s,                      d);
    GLOAD16(s + (size_t)128 * 2048, d + 8192);
  };
  auto stgB = [&](int c, int sl) {
    const char* s = pB + c * 64;
    char* d = ldsb + 81920 + sl * 16384 + dst16;
    GLOAD16(s,                      d);
    GLOAD16(s + (size_t)128 * 2048, d + 8192);
  };

// load chunk's 12 fragments (conflict-free r10 pattern) into parity P
#define LDFR(P, SL)                                                           \
  {                                                                           \
    const char* LA  = ldsb + (SL) * 16384;                                    \
    const char* LB  = ldsb + 81920 + (SL) * 16384;                            \
    const char* ab0 = LA + (wm * 128 + frow) * 64 + xsw;                      \
    const char* bb  = LB + (wn * 64 + frow) * 64 + xsw;                       \
    const char* ab1 = LA + (wm * 128 + 64 + frow) * 64 + xsw;                 \
    fA[P][0] = *(const short8*)(ab0);                                         \
    fB[P][0] = *(const short8*)(bb);                                          \
    fB[P][1] = *(const short8*)(bb + 1024);                                   \
    fB[P][2] = *(const short8*)(bb + 2048);                                   \
    fB[P][3] = *(const short8*)(bb + 3072);                                   \
    fA[P][1] = *(const short8*)(ab0 + 1024);                                  \
    fA[P][2] = *(const short8*)(ab0 + 2048);                                  \
    fA[P][3] = *(const short8*)(ab0 + 3072);                                  \
    fA[P][4] = *(const short8*)(ab1);                                         \
    fA[P][5] = *(const short8*)(ab1 + 1024);                                  \
    fA[P][6] = *(const short8*)(ab1 + 2048);                                  \
    fA[P][7] = *(const short8*)(ab1 + 3072);                                  \
  }

#define MFMA32(P)                                                             \
  {                                                                           \
    __builtin_amdgcn_s_setprio(1);                                            \
    _Pragma("unroll")                                                         \
    for (int i = 0; i < 4; ++i) {                                             \
      _Pragma("unroll")                                                       \
      for (int j = 0; j < 4; ++j) {                                           \
        acc[i][j]     = __builtin_amdgcn_mfma_f32_16x16x32_bf16(fA[P][i],     fB[P][j], acc[i][j],     0, 0, 0); \
        acc[4 + i][j] = __builtin_amdgcn_mfma_f32_16x16x32_bf16(fA[P][4 + i], fB[P][j], acc[4 + i][j], 0, 0, 0); \
      }                                                                       \
    }                                                                         \
    __builtin_amdgcn_s_setprio(0);                                            \
  }

#define BAR __builtin_amdgcn_s_barrier()
#define WAITV(N) asm volatile("s_waitcnt vmcnt(" #N ")" ::: "memory")
// iteration c: wait WN; BAR; read chunk c+1 (slot SLN) -> parity PN;
// stage chunk c+4 -> slot SG; MFMA on parity PC (= c&1).
#define ITER(SLN, PN, SG, STG, WN, PC)                                        \
  {                                                                           \
    WAITV(WN);                                                                \
    BAR;                                                                      \
    LDFR(PN, SLN);                                                            \
    if (STG) { stgA(_c4, SG); stgB(_c4, SG); }                                \
    MFMA32(PC);                                                               \
    ++_c4;                                                                    \
  }

  // prologue: stage chunks 0..3 (slots 0..3); chunk 0 resident; frags(0)->p0
  stgA(0, 0); stgB(0, 0);
  stgA(1, 1); stgB(1, 1);
  stgA(2, 2); stgB(2, 2);
  stgA(3, 3); stgB(3, 3);
  WAITV(12);
  BAR;
  LDFR(0, 0);

  int _c4 = 4;   // chunk to stage this iteration
  ITER(1, 1, 4, true, 8, 0);   // c=0
  ITER(2, 0, 0, true, 8, 1);   // c=1
  ITER(3, 1, 1, true, 8, 0);   // c=2
  ITER(4, 0, 2, true, 8, 1);   // c=3
  ITER(0, 1, 3, true, 8, 0);   // c=4
  ITER(1, 0, 4, true, 8, 1);   // c=5
  ITER(2, 1, 0, true, 8, 0);   // c=6
  ITER(3, 0, 1, true, 8, 1);   // c=7
  ITER(4, 1, 2, true, 8, 0);   // c=8
  ITER(0, 0, 3, true, 8, 1);   // c=9
  ITER(1, 1, 4, true, 8, 0);   // c=10
  ITER(2, 0, 0, true, 8, 1);   // c=11
  ITER(3, 1, 1, true, 8, 0);   // c=12
  ITER(4, 0, 2, true, 8, 1);   // c=13
  ITER(0, 1, 3, true, 8, 0);   // c=14
  ITER(1, 0, 4, true, 8, 1);   // c=15
  ITER(2, 1, 0, true, 8, 0);   // c=16
  ITER(3, 0, 1, true, 8, 1);   // c=17
  ITER(4, 1, 2, true, 8, 0);   // c=18
  ITER(0, 0, 3, true, 8, 1);   // c=19
  ITER(1, 1, 4, true, 8, 0);   // c=20
  ITER(2, 0, 0, true, 8, 1);   // c=21
  ITER(3, 1, 1, true, 8, 0);   // c=22
  ITER(4, 0, 2, true, 8, 1);   // c=23
  ITER(0, 1, 3, true, 8, 0);   // c=24
  ITER(1, 0, 4, true, 8, 1);   // c=25
  ITER(2, 1, 0, true, 8, 0);   // c=26
  ITER(3, 0, 1, true, 8, 1);   // c=27 (stages chunk 31 -> slot 1)
  ITER(4, 1, 0, false, 8, 0);  // c=28
  ITER(0, 0, 0, false, 4, 1);  // c=29
  ITER(1, 1, 0, false, 0, 0);  // c=30 (reads chunk 31 from slot 1)
  MFMA32(1);                   // c=31
#undef ITER
#undef MFMA32
#undef LDFR
#undef WAITV
#undef BAR

  // epilogue: 16x16 C/D mapping col=lane&15, row=(lane>>4)*4+r
  if constexpr (MODE == 0) {
    const int plane = bn >> 10;                 // 0: rem, 1: tanh
    const int cb    = bn & 1023;
    unsigned short* ob = plane ? ob1 : ob0;
    const float* bs    = plane ? bias1 : bias0;
    float bv[4];
    #pragma unroll
    for (int j = 0; j < 4; ++j) bv[j] = bs[cb + wn * 64 + j * 16 + frow];
    #pragma unroll
    for (int ii = 0; ii < 8; ++ii) {
      int row = bm + wm * 128 + ii * 16 + ks * 4;
      #pragma unroll
      for (int j = 0; j < 4; ++j) {
        int col = cb + wn * 64 + j * 16 + frow;
        float lin = (float)col * (1.0f / 1023.0f);
        #pragma unroll
        for (int r = 0; r < 4; ++r) {
          float z = acc[ii][j][r] + bv[j];
          float v;
          if (plane == 0) {
            v = lin / (1.0f + __expf(-z));             // rem (small, bf16-safe)
          } else {
            float e2 = __expf(2.0f * z);
            v = 1.0f - 2.0f / (e2 + 1.0f);             // tanh
          }
          ob[(size_t)(row + r) * D_ + col] = f2bf(v);
        }
      }
    }
  } else {
    float bv[4];
    #pragma unroll
    for (int j = 0; j < 4; ++j) bv[j] = bias0[bn + wn * 64 + j * 16 + frow];
    #pragma unroll
    for (int ii = 0; ii < 8; ++ii) {
      int row = bm + wm * 128 + ii * 16 + ks * 4;
      #pragma unroll
      for (int j = 0; j < 4; ++j) {
        int col = bn + wn * 64 + j * 16 + frow;
        #pragma unroll
        for (int r = 0; r < 4; ++r)
          of[(size_t)(row + r) * D_ + col] = acc[ii][j][r] + bv[j];
      }
    }
  }
}

// ---------------------------------------------------------------------------
// Chunked parallel scan over precomputed (rem, t), 4 channels/thread.
// f = 1 - rem (fp32);  h_t = f*h_{t-1} + t*rem
// ---------------------------------------------------------------------------
__global__ __launch_bounds__(256)
void scan_partial_b(const unsigned short* __restrict__ rb,
                    const unsigned short* __restrict__ tb,
                    float* __restrict__ Ag, float* __restrict__ Ug)
{
  int blk = blockIdx.x;
  int b = blk >> 7, c = blk & (CHUNKS - 1);
  int e = threadIdx.x << 2;
  size_t base = ((size_t)b * L_ + (size_t)c * TCH) * D_ + e;
  f32x4 a = {1.f,1.f,1.f,1.f}, u = {0.f,0.f,0.f,0.f};
  for (int t = 0; t < TCH; ++t) {
    ushort4v r4 = *(const ushort4v*)(rb + base + (size_t)t * D_);
    ushort4v t4 = *(const ushort4v*)(tb + base + (size_t)t * D_);
    #pragma unroll
    for (int j = 0; j < 4; ++j) {
      float rem = bf2f(r4[j]);
      float f   = 1.0f - rem;
      float inp = bf2f(t4[j]) * rem;
      u[j] = fmaf(f, u[j], inp);
      a[j] *= f;
    }
  }
  size_t o = (size_t)(b * CHUNKS + c) * D_ + e;
  *(f32x4*)(Ag + o) = a;
  *(f32x4*)(Ug + o) = u;
}

__global__ __launch_bounds__(256)
void scan_carry(const float* __restrict__ Ag, const float* __restrict__ Ug,
                const float* __restrict__ hidden, float* __restrict__ Hin)
{
  int gid = blockIdx.x * 256 + threadIdx.x;  // B_*D_/4 threads
  int b = gid >> 8;
  int e = (gid & 255) << 2;
  f32x4 h = *(const f32x4*)(hidden + (size_t)b * D_ + e);
  for (int c = 0; c < CHUNKS; ++c) {
    size_t o = (size_t)(b * CHUNKS + c) * D_ + e;
    *(f32x4*)(Hin + o) = h;
    f32x4 A = *(const f32x4*)(Ag + o);
    f32x4 U = *(const f32x4*)(Ug + o);
    h = A * h + U;
  }
}

__global__ __launch_bounds__(256)
void scan_apply_b(const unsigned short* __restrict__ rb,
                  const unsigned short* __restrict__ tb,
                  const float* __restrict__ Hin,
                  float* __restrict__ hout, unsigned short* __restrict__ hb)
{
  int blk = blockIdx.x;
  int b = blk >> 7, c = blk & (CHUNKS - 1);
  int e = threadIdx.x << 2;
  size_t base = ((size_t)b * L_ + (size_t)c * TCH) * D_ + e;
  f32x4 h = *(const f32x4*)(Hin + (size_t)(b * CHUNKS + c) * D_ + e);
  for (int t = 0; t < TCH; ++t) {
    size_t o = base + (size_t)t * D_;
    ushort4v r4 = *(const ushort4v*)(rb + o);
    ushort4v t4 = *(const ushort4v*)(tb + o);
    #pragma unroll
    for (int j = 0; j < 4; ++j) {
      float rem = bf2f(r4[j]);
      float f   = 1.0f - rem;
      float inp = bf2f(t4[j]) * rem;
      h[j] = fmaf(f, h[j], inp);
    }
    *(f32x4*)(hout + o) = h;
    ushort4v p;
    p[0] = f2bf(h[0]); p[1] = f2bf(h[1]); p[2] = f2bf(h[2]); p[3] = f2bf(h[3]);
    *(ushort4v*)(hb + o) = p;
  }
}

// ---------------------------------------------------------------------------
// Slow fallback (fp32 in) — only if ws too small (never expected).
// ---------------------------------------------------------------------------
template<int MODE>
__global__ __launch_bounds__(256, 2)
void gemm_slow(const float* __restrict__ A, const float* __restrict__ B0,
               const float* __restrict__ B1, const float* __restrict__ bias0,
               const float* __restrict__ bias1, float* __restrict__ out0,
               float* __restrict__ out1)
{
  constexpr int BK = 32;
  __shared__ unsigned short As[128 * BK];
  __shared__ unsigned short Bs0[128 * BK];
  __shared__ unsigned short Bs1[(MODE == 0) ? (128 * BK) : 8];

  const int tid = threadIdx.x, lane = tid & 63, wave = tid >> 6;
  const int wr = wave >> 1, wc = wave & 1;
  const int bm = blockIdx.x * 128, bn = blockIdx.y * 128;
  f32x4 acc0[4][4] = {};
  f32x4 acc1[(MODE == 0) ? 4 : 1][(MODE == 0) ? 4 : 1] = {};
  const int frow = lane & 15, kslot = lane >> 4;
  const int xs = kslot ^ (frow & 3);

  auto stage = [&](const float* src, unsigned short* dst) {
    #pragma unroll
    for (int p = 0; p < 4; ++p) {
      int g = p * 256 + tid;
      int row = g >> 3, kq = (g & 7) << 2;
      f32x4 v = *(const f32x4*)(src + (size_t)row * D_ + kq);
      ushort4v w;
      w[0] = f2bf(v[0]); w[1] = f2bf(v[1]); w[2] = f2bf(v[2]); w[3] = f2bf(v[3]);
      int byte = kq << 1, slot = byte >> 4, sub = byte & 15;
      int off = row * 64 + ((slot ^ (row & 3)) << 4) + sub;
      *(ushort4v*)((char*)dst + off) = w;
    }
  };

  for (int k0 = 0; k0 < D_; k0 += BK) {
    stage(A + (size_t)bm * D_ + k0, As);
    stage(B0 + (size_t)bn * D_ + k0, Bs0);
    if constexpr (MODE == 0) stage(B1 + (size_t)bn * D_ + k0, Bs1);
    __syncthreads();
    short8 af[4], bf0[4], bf1[4];
    #pragma unroll
    for (int i = 0; i < 4; ++i) {
      int ar = wr * 64 + i * 16 + frow;
      af[i] = *(const short8*)((const char*)As + ar * 64 + (xs << 4));
      int br = wc * 64 + i * 16 + frow;
      bf0[i] = *(const short8*)((const char*)Bs0 + br * 64 + (xs << 4));
      if constexpr (MODE == 0)
        bf1[i] = *(const short8*)((const char*)Bs1 + br * 64 + (xs << 4));
    }
    #pragma unroll
    for (int i = 0; i < 4; ++i)
      #pragma unroll
      for (int j = 0; j < 4; ++j) {
        acc0[i][j] = __builtin_amdgcn_mfma_f32_16x16x32_bf16(af[i], bf0[j], acc0[i][j], 0, 0, 0);
        if constexpr (MODE == 0)
          acc1[i][j] = __builtin_amdgcn_mfma_f32_16x16x32_bf16(af[i], bf1[j], acc1[i][j], 0, 0, 0);
      }
    __syncthreads();
  }
  #pragma unroll
  for (int i = 0; i < 4; ++i)
    #pragma unroll
    for (int j = 0; j < 4; ++j)
      #pragma unroll
      for (int r = 0; r < 4; ++r) {
        int row = bm + wr * 64 + i * 16 + (lane >> 4) * 4 + r;
        int col = bn + wc * 64 + j * 16 + (lane & 15);
        size_t idx = (size_t)row * D_ + col;
        if constexpr (MODE == 0) {
          float zf = acc0[i][j][r] + bias0[col];
          float linv = (float)col * (1.0f / 1023.0f);
          float rem = linv / (1.0f + __expf(-zf));
          float zi = acc1[i][j][r] + bias1[col];
          float e2 = __expf(2.0f * zi);
          float th = 1.0f - 2.0f / (e2 + 1.0f);
          out0[idx] = 1.0f - rem;
          out1[idx] = th * rem;
        } else {
          out0[idx] = acc0[i][j][r] + bias0[col];
        }
      }
}

__global__ __launch_bounds__(256)
void scan_partial_f(const float* __restrict__ p0, const float* __restrict__ p1,
                    float* __restrict__ Ag, float* __restrict__ Ug)
{
  int blk = blockIdx.x;
  int b = blk / (CHUNKS * 2);
  int c = (blk >> 1) & (CHUNKS - 1);
  int e = ((blk & 1) << 9) + threadIdx.x * 2;
  size_t base = ((size_t)b * L_ + (size_t)c * TCH) * D_ + e;
  f32x2 a = {1.0f, 1.0f}, u = {0.0f, 0.0f};
  for (int t = 0; t < TCH; ++t) {
    f32x2 f = *(const f32x2*)(p0 + base + (size_t)t * D_);
    f32x2 i = *(const f32x2*)(p1 + base + (size_t)t * D_);
    u = f * u + i;
    a = a * f;
  }
  size_t o = (size_t)(b * CHUNKS + c) * D_ + e;
  *(f32x2*)(Ag + o) = a;
  *(f32x2*)(Ug + o) = u;
}

__global__ __launch_bounds__(256)
void scan_apply_f(const float* __restrict__ p0, float* __restrict__ p1_io,
                  const float* __restrict__ Hin)
{
  int blk = blockIdx.x;
  int b = blk / (CHUNKS * 2);
  int c = (blk >> 1) & (CHUNKS - 1);
  int e = ((blk & 1) << 9) + threadIdx.x * 2;
  size_t base = ((size_t)b * L_ + (size_t)c * TCH) * D_ + e;
  f32x2 h = *(const f32x2*)(Hin + (size_t)(b * CHUNKS + c) * D_ + e);
  for (int t = 0; t < TCH; ++t) {
    size_t o = base + (size_t)t * D_;
    f32x2 f = *(const f32x2*)(p0 + o);
    f32x2 i = *(const f32x2*)(p1_io + o);
    h = f * h + i;
    *(f32x2*)(p1_io + o) = h;
  }
}

// ---------------------------------------------------------------------------
extern "C" void kernel_launch(void* const* d_in, const int* in_sizes, int n_in,
                              void* d_out, int out_size, void* d_ws, size_t ws_size,
                              hipStream_t stream)
{
  const float* x      = (const float*)d_in[0];
  const float* hidden = (const float*)d_in[1];
  const float* W_f    = (const float*)d_in[2];
  const float* b_f    = (const float*)d_in[3];
  const float* W_i    = (const float*)d_in[4];
  const float* b_i    = (const float*)d_in[5];
  const float* W_o    = (const float*)d_in[6];
  const float* b_o    = (const float*)d_in[7];

  float* y = (float*)d_out;
  float* h = y + (size_t)M_ * D_;

  const size_t xb_elems = (size_t)M_ * D_;
  const size_t w_elems  = (size_t)D_ * D_;
  const size_t agg      = (size_t)B_ * CHUNKS * D_;
  const size_t need = (xb_elems * 3 + 3 * w_elems) * 2 + agg * 3 * 4;

  if (ws_size >= need) {
    unsigned short* xb  = (unsigned short*)d_ws;       // bf16 x, later bf16 h
    unsigned short* wfb = xb + xb_elems;               // [W_f;W_i] stacked
    unsigned short* wib = wfb + w_elems;
    unsigned short* wob = wib + w_elems;
    unsigned short* rbv = wob + w_elems;               // bf16 rem
    unsigned short* tbv = rbv + xb_elems;              // bf16 tanh
    float* Ag  = (float*)(tbv + xb_elems);
    float* Ug  = Ag + agg;
    float* Hin = Ug + agg;

    cvt_bf16<<<(int)(xb_elems / 8 / 256), 256, 0, stream>>>(x, xb, (int)(xb_elems / 8));
    cvt_w3<<<3 * (int)(w_elems / 8 / 256), 256, 0, stream>>>(W_f, W_i, W_o, wfb);

    gemm256<0><<<1024, 512, 0, stream>>>(xb, wfb, b_f, b_i, rbv, tbv, nullptr);

    int pblocks = B_ * CHUNKS;               // 1024
    scan_partial_b<<<pblocks, 256, 0, stream>>>(rbv, tbv, Ag, Ug);
    scan_carry<<<(B_ * D_ / 4) / 256, 256, 0, stream>>>(Ag, Ug, hidden, Hin);
    scan_apply_b<<<pblocks, 256, 0, stream>>>(rbv, tbv, Hin, h, xb);

    gemm256<1><<<512, 512, 0, stream>>>(xb, wob, b_o, nullptr, nullptr, nullptr, y);
  } else {
    float* Ag  = (float*)d_ws;
    float* Ug  = Ag + agg;
    float* Hin = Ug + agg;
    dim3 gg(M_ / 128, D_ / 128);
    int pblocks = B_ * CHUNKS * 2;

    gemm_slow<0><<<gg, 256, 0, stream>>>(x, W_f, W_i, b_f, b_i, y, h);
    scan_partial_f<<<pblocks, 256, 0, stream>>>(y, h, Ag, Ug);
    scan_carry<<<(B_ * D_ / 4) / 256, 256, 0, stream>>>(Ag, Ug, hidden, Hin);
    scan_apply_f<<<pblocks, 256, 0, stream>>>(y, h, Hin);
    gemm_slow<1><<<gg, 256, 0, stream>>>(h, W_o, nullptr, b_o, nullptr, y, nullptr);
  }
}

// Round 13
// 393.777 us; speedup vs baseline: 1.0132x; 1.0125x over previous
//
#include <hip/hip_runtime.h>
#include <stdint.h>

#define B_ 8
#define L_ 4096
#define D_ 1024
#define M_ (B_*L_)        // 32768 rows
#define CHUNKS 128
#define TCH (L_/CHUNKS)   // 32

typedef float f32x4 __attribute__((ext_vector_type(4)));
typedef float f32x2 __attribute__((ext_vector_type(2)));
typedef short short8 __attribute__((ext_vector_type(8)));
typedef unsigned short ushort4v __attribute__((ext_vector_type(4)));

static __device__ __forceinline__ unsigned short f2bf(float f) {
  union { float f; unsigned u; } v; v.f = f;
  unsigned r = v.u + 0x7FFFu + ((v.u >> 16) & 1u);   // round-to-nearest-even
  return (unsigned short)(r >> 16);
}
static __device__ __forceinline__ float bf2f(unsigned short u) {
  union { unsigned u; float f; } v; v.u = ((unsigned)u) << 16; return v.f;
}

#define GLOAD16(g, l) \
  __builtin_amdgcn_global_load_lds((__attribute__((address_space(1))) const void*)(g), \
                                   (__attribute__((address_space(3))) void*)(l), 16, 0, 0)

// ---------------------------------------------------------------------------
// fp32 -> bf16 convert: x + W_f + W_i + W_o in ONE launch.
// dst layout is contiguous in ws: [xb | wfb | wib | wob], so dst off = gid*8.
// ---------------------------------------------------------------------------
__global__ __launch_bounds__(256)
void cvt_all(const float* __restrict__ x,  const float* __restrict__ w0,
             const float* __restrict__ w1, const float* __restrict__ w2,
             unsigned short* __restrict__ dst)
{
  const int xn8 = (M_ * D_) / 8;       // 4,194,304
  const int wn8 = (D_ * D_) / 8;       // 131,072
  int gid = blockIdx.x * 256 + threadIdx.x;
  const float* src;
  size_t soff;
  if (gid < xn8)                { src = x;  soff = (size_t)gid * 8; }
  else if (gid < xn8 + wn8)     { src = w0; soff = (size_t)(gid - xn8) * 8; }
  else if (gid < xn8 + 2 * wn8) { src = w1; soff = (size_t)(gid - xn8 - wn8) * 8; }
  else                          { src = w2; soff = (size_t)(gid - xn8 - 2 * wn8) * 8; }
  const f32x4* s = (const f32x4*)(src + soff);
  f32x4 v0 = s[0], v1 = s[1];
  union { short8 v; unsigned short u[8]; } w;
  w.u[0] = f2bf(v0[0]); w.u[1] = f2bf(v0[1]); w.u[2] = f2bf(v0[2]); w.u[3] = f2bf(v0[3]);
  w.u[4] = f2bf(v1[0]); w.u[5] = f2bf(v1[1]); w.u[6] = f2bf(v1[2]); w.u[7] = f2bf(v1[3]);
  *(short8*)(dst + (size_t)gid * 8) = w.v;
}

// ---------------------------------------------------------------------------
// 256x256 8-wave GEMM. Ring-5 chunk pipeline (r10, best variant):
//   chunk = 32 K-cols (16 KB); A ring-5 (80KB) + B ring-5 (80KB @ +81920).
//   Chunk c staged during chunk c-4 -> 4-chunk issue->use lead for BOTH.
// Per chunk: {ldB4+ldA(ih0); stgA(c+4); 16 MFMA; ldA(ih1); stgB(c+4);
//   16 MFMA; vmcnt(12) [drains exactly chunk c+1]; barrier}.
// NO setprio: T5 is measured-negative on non-8-phase GEMM (m190).
// Conflict-free fragment reads (PMC=0); slot-XOR swizzle via pre-swizzled
// global source (rule 21).
// MODE 0: stacked gates Bw=[W_f;W_i]; writes rem=lin*sig(zf+b), t=tanh(zi+b)
// MODE 1: y = h*W_o^T + b_o fp32.
// A-locality dispatch: 32 co-resident blocks/XCD = {GBM bm} x {all bn}.
// NOTE: six schedule variants (r8-r12) all plateau at 34-36% MfmaUtil =
// the documented m97-class plain-HIP structural ceiling (~820-900 TF).
// ---------------------------------------------------------------------------
template<int MODE>
__global__ __launch_bounds__(512, 2)
void gemm256(const unsigned short* __restrict__ A,
             const unsigned short* __restrict__ Bw,
             const float* __restrict__ bias0,
             const float* __restrict__ bias1,
             unsigned short* __restrict__ ob0,   // rem (MODE 0)
             unsigned short* __restrict__ ob1,   // t   (MODE 0)
             float* __restrict__ of)             // y   (MODE 1)
{
  __shared__ unsigned short lds[81920];   // 160 KB: A slots 0..4 | B slots at +81920
  char* ldsb = (char*)lds;

  const int tid  = threadIdx.x;
  const int lane = tid & 63;
  const int wid  = tid >> 6;
  const int wm   = wid >> 2;          // 0..1
  const int wn   = wid & 3;           // 0..3
  const int frow = lane & 15, ks = lane >> 4;
  const int xsw  = (ks ^ ((frow >> 1) & 3)) << 4;

  constexpr int NBN = (MODE == 0) ? 8 : 4;
  constexpr int GBM = 32 / NBN;
  const int xcd   = blockIdx.x & 7;
  const int slot  = blockIdx.x >> 3;
  const int local = slot & 31;
  const int wrnd  = slot >> 5;
  const int bm = (xcd * 16 + wrnd * GBM + (local & (GBM - 1))) * 256;
  const int bn = (local / GBM) * 256;

  const int r0  = tid >> 2;
  const int scl = ((tid & 3) ^ ((r0 >> 1) & 3)) << 4;   // pre-swizzled source slot
  const char* pA = (const char*)A  + (size_t)(bm + r0) * 2048 + scl;
  const char* pB = (const char*)Bw + (size_t)(bn + r0) * 2048 + scl;
  const int dst16 = tid * 16;

  f32x4 acc[8][4] = {};
  short8 aq[4], bq[4];

  // stage one 16KB chunk (32 K-cols) = 2 gload16/thread
  auto stgA = [&](int c, int sl) {
    const char* s = pA + c * 64;
    char* d = ldsb + sl * 16384 + dst16;
    GLOAD16(s,                      d);
    GLOAD16(s + (size_t)128 * 2048, d + 8192);
  };
  auto stgB = [&](int c, int sl) {
    const char* s = pB + c * 64;
    char* d = ldsb + 81920 + sl * 16384 + dst16;
    GLOAD16(s,                      d);
    GLOAD16(s + (size_t)128 * 2048, d + 8192);
  };
  auto ldAB4 = [&](const char* LA, const char* LB) {   // B frags + A ih0 rows
    const char* ab = LA + (wm * 128 + frow) * 64 + xsw;
    const char* bb = LB + (wn * 64 + frow) * 64 + xsw;
    aq[0] = *(const short8*)(ab);
    bq[0] = *(const short8*)(bb);
    bq[1] = *(const short8*)(bb + 1024);
    bq[2] = *(const short8*)(bb + 2048);
    bq[3] = *(const short8*)(bb + 3072);
    aq[1] = *(const short8*)(ab + 1024);
    aq[2] = *(const short8*)(ab + 2048);
    aq[3] = *(const short8*)(ab + 3072);
  };
  auto ldA4 = [&](const char* LA) {                    // A ih1 rows (+64)
    const char* ab = LA + (wm * 128 + 64 + frow) * 64 + xsw;
    aq[0] = *(const short8*)(ab);
    aq[1] = *(const short8*)(ab + 1024);
    aq[2] = *(const short8*)(ab + 2048);
    aq[3] = *(const short8*)(ab + 3072);
  };
  auto mfma16 = [&](int ih) {
    #pragma unroll
    for (int i2 = 0; i2 < 4; ++i2) {
      #pragma unroll
      for (int j = 0; j < 4; ++j)
        acc[ih * 4 + i2][j] =
          __builtin_amdgcn_mfma_f32_16x16x32_bf16(aq[i2], bq[j], acc[ih * 4 + i2][j], 0, 0, 0);
    }
  };

#define BAR __builtin_amdgcn_s_barrier()
#define WAITV(N) asm volatile("s_waitcnt vmcnt(" #N ")" ::: "memory")
// chunk c: read slot SL; stage chunk c+4 -> slot SG; wait WN drains chunk c+1
#define DO_CH(c, SL, SG, STG, WN)                                             \
  {                                                                           \
    const char* LA = ldsb + (SL) * 16384;                                     \
    const char* LB = ldsb + 81920 + (SL) * 16384;                             \
    ldAB4(LA, LB);                                                            \
    if (STG) stgA((c) + 4, (SG));                                             \
    mfma16(0);                                                                \
    ldA4(LA);                                                                 \
    if (STG) stgB((c) + 4, (SG));                                             \
    mfma16(1);                                                                \
    WAITV(WN);                                                                \
    BAR;                                                                      \
  }
#define DO_CH_LAST(SL)                                                        \
  {                                                                           \
    const char* LA = ldsb + (SL) * 16384;                                     \
    const char* LB = ldsb + 81920 + (SL) * 16384;                             \
    ldAB4(LA, LB);                                                            \
    mfma16(0);                                                                \
    ldA4(LA);                                                                 \
    mfma16(1);                                                                \
  }

  // prologue: chunks 0..3 (A,B interleaved; oldest = chunk 0) -> 16 loads
  stgA(0, 0); stgB(0, 0);
  stgA(1, 1); stgB(1, 1);
  stgA(2, 2); stgB(2, 2);
  stgA(3, 3); stgB(3, 3);
  WAITV(12);                          // chunk 0 resident
  BAR;

  DO_CH( 0, 0, 4, true, 12);
  DO_CH( 1, 1, 0, true, 12);
  DO_CH( 2, 2, 1, true, 12);
  DO_CH( 3, 3, 2, true, 12);
  DO_CH( 4, 4, 3, true, 12);
  DO_CH( 5, 0, 4, true, 12);
  DO_CH( 6, 1, 0, true, 12);
  DO_CH( 7, 2, 1, true, 12);
  DO_CH( 8, 3, 2, true, 12);
  DO_CH( 9, 4, 3, true, 12);
  DO_CH(10, 0, 4, true, 12);
  DO_CH(11, 1, 0, true, 12);
  DO_CH(12, 2, 1, true, 12);
  DO_CH(13, 3, 2, true, 12);
  DO_CH(14, 4, 3, true, 12);
  DO_CH(15, 0, 4, true, 12);
  DO_CH(16, 1, 0, true, 12);
  DO_CH(17, 2, 1, true, 12);
  DO_CH(18, 3, 2, true, 12);
  DO_CH(19, 4, 3, true, 12);
  DO_CH(20, 0, 4, true, 12);
  DO_CH(21, 1, 0, true, 12);
  DO_CH(22, 2, 1, true, 12);
  DO_CH(23, 3, 2, true, 12);
  DO_CH(24, 4, 3, true, 12);
  DO_CH(25, 0, 4, true, 12);
  DO_CH(26, 1, 0, true, 12);
  DO_CH(27, 2, 1, true, 12);   // stages chunk 31 (last)
  DO_CH(28, 3, 0, false, 8);
  DO_CH(29, 4, 0, false, 4);
  DO_CH(30, 0, 0, false, 0);
  DO_CH_LAST(1);
#undef DO_CH
#undef DO_CH_LAST
#undef WAITV
#undef BAR

  // epilogue: C/D mapping col=lane&15, row=(lane>>4)*4+r
  if constexpr (MODE == 0) {
    const int plane = bn >> 10;                 // 0: rem, 1: tanh
    const int cb    = bn & 1023;
    unsigned short* ob = plane ? ob1 : ob0;
    const float* bs    = plane ? bias1 : bias0;
    float bv[4];
    #pragma unroll
    for (int j = 0; j < 4; ++j) bv[j] = bs[cb + wn * 64 + j * 16 + frow];
    #pragma unroll
    for (int ii = 0; ii < 8; ++ii) {
      int row = bm + wm * 128 + ii * 16 + ks * 4;
      #pragma unroll
      for (int j = 0; j < 4; ++j) {
        int col = cb + wn * 64 + j * 16 + frow;
        float lin = (float)col * (1.0f / 1023.0f);
        #pragma unroll
        for (int r = 0; r < 4; ++r) {
          float z = acc[ii][j][r] + bv[j];
          float v;
          if (plane == 0) {
            v = lin / (1.0f + __expf(-z));             // rem (small, bf16-safe)
          } else {
            float e2 = __expf(2.0f * z);
            v = 1.0f - 2.0f / (e2 + 1.0f);             // tanh
          }
          ob[(size_t)(row + r) * D_ + col] = f2bf(v);
        }
      }
    }
  } else {
    float bv[4];
    #pragma unroll
    for (int j = 0; j < 4; ++j) bv[j] = bias0[bn + wn * 64 + j * 16 + frow];
    #pragma unroll
    for (int ii = 0; ii < 8; ++ii) {
      int row = bm + wm * 128 + ii * 16 + ks * 4;
      #pragma unroll
      for (int j = 0; j < 4; ++j) {
        int col = bn + wn * 64 + j * 16 + frow;
        #pragma unroll
        for (int r = 0; r < 4; ++r)
          of[(size_t)(row + r) * D_ + col] = acc[ii][j][r] + bv[j];
      }
    }
  }
}

// ---------------------------------------------------------------------------
// Chunked parallel scan over precomputed (rem, t), 4 channels/thread.
// f = 1 - rem (fp32);  h_t = f*h_{t-1} + t*rem
// ---------------------------------------------------------------------------
__global__ __launch_bounds__(256)
void scan_partial_b(const unsigned short* __restrict__ rb,
                    const unsigned short* __restrict__ tb,
                    float* __restrict__ Ag, float* __restrict__ Ug)
{
  int blk = blockIdx.x;
  int b = blk >> 7, c = blk & (CHUNKS - 1);
  int e = threadIdx.x << 2;
  size_t base = ((size_t)b * L_ + (size_t)c * TCH) * D_ + e;
  f32x4 a = {1.f,1.f,1.f,1.f}, u = {0.f,0.f,0.f,0.f};
  for (int t = 0; t < TCH; ++t) {
    ushort4v r4 = *(const ushort4v*)(rb + base + (size_t)t * D_);
    ushort4v t4 = *(const ushort4v*)(tb + base + (size_t)t * D_);
    #pragma unroll
    for (int j = 0; j < 4; ++j) {
      float rem = bf2f(r4[j]);
      float f   = 1.0f - rem;
      float inp = bf2f(t4[j]) * rem;
      u[j] = fmaf(f, u[j], inp);
      a[j] *= f;
    }
  }
  size_t o = (size_t)(b * CHUNKS + c) * D_ + e;
  *(f32x4*)(Ag + o) = a;
  *(f32x4*)(Ug + o) = u;
}

__global__ __launch_bounds__(256)
void scan_carry(const float* __restrict__ Ag, const float* __restrict__ Ug,
                const float* __restrict__ hidden, float* __restrict__ Hin)
{
  int gid = blockIdx.x * 256 + threadIdx.x;  // B_*D_/4 threads
  int b = gid >> 8;
  int e = (gid & 255) << 2;
  f32x4 h = *(const f32x4*)(hidden + (size_t)b * D_ + e);
  for (int c = 0; c < CHUNKS; ++c) {
    size_t o = (size_t)(b * CHUNKS + c) * D_ + e;
    *(f32x4*)(Hin + o) = h;
    f32x4 A = *(const f32x4*)(Ag + o);
    f32x4 U = *(const f32x4*)(Ug + o);
    h = A * h + U;
  }
}

__global__ __launch_bounds__(256)
void scan_apply_b(const unsigned short* __restrict__ rb,
                  const unsigned short* __restrict__ tb,
                  const float* __restrict__ Hin,
                  float* __restrict__ hout, unsigned short* __restrict__ hb)
{
  int blk = blockIdx.x;
  int b = blk >> 7, c = blk & (CHUNKS - 1);
  int e = threadIdx.x << 2;
  size_t base = ((size_t)b * L_ + (size_t)c * TCH) * D_ + e;
  f32x4 h = *(const f32x4*)(Hin + (size_t)(b * CHUNKS + c) * D_ + e);
  for (int t = 0; t < TCH; ++t) {
    size_t o = base + (size_t)t * D_;
    ushort4v r4 = *(const ushort4v*)(rb + o);
    ushort4v t4 = *(const ushort4v*)(tb + o);
    #pragma unroll
    for (int j = 0; j < 4; ++j) {
      float rem = bf2f(r4[j]);
      float f   = 1.0f - rem;
      float inp = bf2f(t4[j]) * rem;
      h[j] = fmaf(f, h[j], inp);
    }
    *(f32x4*)(hout + o) = h;
    ushort4v p;
    p[0] = f2bf(h[0]); p[1] = f2bf(h[1]); p[2] = f2bf(h[2]); p[3] = f2bf(h[3]);
    *(ushort4v*)(hb + o) = p;
  }
}

// ---------------------------------------------------------------------------
// Slow fallback (fp32 in) — only if ws too small (never expected).
// ---------------------------------------------------------------------------
template<int MODE>
__global__ __launch_bounds__(256, 2)
void gemm_slow(const float* __restrict__ A, const float* __restrict__ B0,
               const float* __restrict__ B1, const float* __restrict__ bias0,
               const float* __restrict__ bias1, float* __restrict__ out0,
               float* __restrict__ out1)
{
  constexpr int BK = 32;
  __shared__ unsigned short As[128 * BK];
  __shared__ unsigned short Bs0[128 * BK];
  __shared__ unsigned short Bs1[(MODE == 0) ? (128 * BK) : 8];

  const int tid = threadIdx.x, lane = tid & 63, wave = tid >> 6;
  const int wr = wave >> 1, wc = wave & 1;
  const int bm = blockIdx.x * 128, bn = blockIdx.y * 128;
  f32x4 acc0[4][4] = {};
  f32x4 acc1[(MODE == 0) ? 4 : 1][(MODE == 0) ? 4 : 1] = {};
  const int frow = lane & 15, kslot = lane >> 4;
  const int xs = kslot ^ (frow & 3);

  auto stage = [&](const float* src, unsigned short* dst) {
    #pragma unroll
    for (int p = 0; p < 4; ++p) {
      int g = p * 256 + tid;
      int row = g >> 3, kq = (g & 7) << 2;
      f32x4 v = *(const f32x4*)(src + (size_t)row * D_ + kq);
      ushort4v w;
      w[0] = f2bf(v[0]); w[1] = f2bf(v[1]); w[2] = f2bf(v[2]); w[3] = f2bf(v[3]);
      int byte = kq << 1, slot = byte >> 4, sub = byte & 15;
      int off = row * 64 + ((slot ^ (row & 3)) << 4) + sub;
      *(ushort4v*)((char*)dst + off) = w;
    }
  };

  for (int k0 = 0; k0 < D_; k0 += BK) {
    stage(A + (size_t)bm * D_ + k0, As);
    stage(B0 + (size_t)bn * D_ + k0, Bs0);
    if constexpr (MODE == 0) stage(B1 + (size_t)bn * D_ + k0, Bs1);
    __syncthreads();
    short8 af[4], bf0[4], bf1[4];
    #pragma unroll
    for (int i = 0; i < 4; ++i) {
      int ar = wr * 64 + i * 16 + frow;
      af[i] = *(const short8*)((const char*)As + ar * 64 + (xs << 4));
      int br = wc * 64 + i * 16 + frow;
      bf0[i] = *(const short8*)((const char*)Bs0 + br * 64 + (xs << 4));
      if constexpr (MODE == 0)
        bf1[i] = *(const short8*)((const char*)Bs1 + br * 64 + (xs << 4));
    }
    #pragma unroll
    for (int i = 0; i < 4; ++i)
      #pragma unroll
      for (int j = 0; j < 4; ++j) {
        acc0[i][j] = __builtin_amdgcn_mfma_f32_16x16x32_bf16(af[i], bf0[j], acc0[i][j], 0, 0, 0);
        if constexpr (MODE == 0)
          acc1[i][j] = __builtin_amdgcn_mfma_f32_16x16x32_bf16(af[i], bf1[j], acc1[i][j], 0, 0, 0);
      }
    __syncthreads();
  }
  #pragma unroll
  for (int i = 0; i < 4; ++i)
    #pragma unroll
    for (int j = 0; j < 4; ++j)
      #pragma unroll
      for (int r = 0; r < 4; ++r) {
        int row = bm + wr * 64 + i * 16 + (lane >> 4) * 4 + r;
        int col = bn + wc * 64 + j * 16 + (lane & 15);
        size_t idx = (size_t)row * D_ + col;
        if constexpr (MODE == 0) {
          float zf = acc0[i][j][r] + bias0[col];
          float linv = (float)col * (1.0f / 1023.0f);
          float rem = linv / (1.0f + __expf(-zf));
          float zi = acc1[i][j][r] + bias1[col];
          float e2 = __expf(2.0f * zi);
          float th = 1.0f - 2.0f / (e2 + 1.0f);
          out0[idx] = 1.0f - rem;
          out1[idx] = th * rem;
        } else {
          out0[idx] = acc0[i][j][r] + bias0[col];
        }
      }
}

__global__ __launch_bounds__(256)
void scan_partial_f(const float* __restrict__ p0, const float* __restrict__ p1,
                    float* __restrict__ Ag, float* __restrict__ Ug)
{
  int blk = blockIdx.x;
  int b = blk / (CHUNKS * 2);
  int c = (blk >> 1) & (CHUNKS - 1);
  int e = ((blk & 1) << 9) + threadIdx.x * 2;
  size_t base = ((size_t)b * L_ + (size_t)c * TCH) * D_ + e;
  f32x2 a = {1.0f, 1.0f}, u = {0.0f, 0.0f};
  for (int t = 0; t < TCH; ++t) {
    f32x2 f = *(const f32x2*)(p0 + base + (size_t)t * D_);
    f32x2 i = *(const f32x2*)(p1 + base + (size_t)t * D_);
    u = f * u + i;
    a = a * f;
  }
  size_t o = (size_t)(b * CHUNKS + c) * D_ + e;
  *(f32x2*)(Ag + o) = a;
  *(f32x2*)(Ug + o) = u;
}

__global__ __launch_bounds__(256)
void scan_apply_f(const float* __restrict__ p0, float* __restrict__ p1_io,
                  const float* __restrict__ Hin)
{
  int blk = blockIdx.x;
  int b = blk / (CHUNKS * 2);
  int c = (blk >> 1) & (CHUNKS - 1);
  int e = ((blk & 1) << 9) + threadIdx.x * 2;
  size_t base = ((size_t)b * L_ + (size_t)c * TCH) * D_ + e;
  f32x2 h = *(const f32x2*)(Hin + (size_t)(b * CHUNKS + c) * D_ + e);
  for (int t = 0; t < TCH; ++t) {
    size_t o = base + (size_t)t * D_;
    f32x2 f = *(const f32x2*)(p0 + o);
    f32x2 i = *(const f32x2*)(p1_io + o);
    h = f * h + i;
    *(f32x2*)(p1_io + o) = h;
  }
}

// ---------------------------------------------------------------------------
extern "C" void kernel_launch(void* const* d_in, const int* in_sizes, int n_in,
                              void* d_out, int out_size, void* d_ws, size_t ws_size,
                              hipStream_t stream)
{
  const float* x      = (const float*)d_in[0];
  const float* hidden = (const float*)d_in[1];
  const float* W_f    = (const float*)d_in[2];
  const float* b_f    = (const float*)d_in[3];
  const float* W_i    = (const float*)d_in[4];
  const float* b_i    = (const float*)d_in[5];
  const float* W_o    = (const float*)d_in[6];
  const float* b_o    = (const float*)d_in[7];

  float* y = (float*)d_out;
  float* h = y + (size_t)M_ * D_;

  const size_t xb_elems = (size_t)M_ * D_;
  const size_t w_elems  = (size_t)D_ * D_;
  const size_t agg      = (size_t)B_ * CHUNKS * D_;
  const size_t need = (xb_elems * 3 + 3 * w_elems) * 2 + agg * 3 * 4;

  if (ws_size >= need) {
    unsigned short* xb  = (unsigned short*)d_ws;       // bf16 x, later bf16 h
    unsigned short* wfb = xb + xb_elems;               // [W_f;W_i] stacked
    unsigned short* wib = wfb + w_elems;
    unsigned short* wob = wib + w_elems;
    unsigned short* rbv = wob + w_elems;               // bf16 rem
    unsigned short* tbv = rbv + xb_elems;              // bf16 tanh
    float* Ag  = (float*)(tbv + xb_elems);
    float* Ug  = Ag + agg;
    float* Hin = Ug + agg;

    int cblk = (int)((xb_elems + 3 * w_elems) / 8 / 256);   // 17920
    cvt_all<<<cblk, 256, 0, stream>>>(x, W_f, W_i, W_o, xb);

    gemm256<0><<<1024, 512, 0, stream>>>(xb, wfb, b_f, b_i, rbv, tbv, nullptr);

    int pblocks = B_ * CHUNKS;               // 1024
    scan_partial_b<<<pblocks, 256, 0, stream>>>(rbv, tbv, Ag, Ug);
    scan_carry<<<(B_ * D_ / 4) / 256, 256, 0, stream>>>(Ag, Ug, hidden, Hin);
    scan_apply_b<<<pblocks, 256, 0, stream>>>(rbv, tbv, Hin, h, xb);

    gemm256<1><<<512, 512, 0, stream>>>(xb, wob, b_o, nullptr, nullptr, nullptr, y);
  } else {
    float* Ag  = (float*)d_ws;
    float* Ug  = Ag + agg;
    float* Hin = Ug + agg;
    dim3 gg(M_ / 128, D_ / 128);
    int pblocks = B_ * CHUNKS * 2;

    gemm_slow<0><<<gg, 256, 0, stream>>>(x, W_f, W_i, b_f, b_i, y, h);
    scan_partial_f<<<pblocks, 256, 0, stream>>>(y, h, Ag, Ug);
    scan_carry<<<(B_ * D_ / 4) / 256, 256, 0, stream>>>(Ag, Ug, hidden, Hin);
    scan_apply_f<<<pblocks, 256, 0, stream>>>(y, h, Hin);
    gemm_slow<1><<<gg, 256, 0, stream>>>(h, W_o, nullptr, b_o, nullptr, y, nullptr);
  }
}

// Round 14
// 390.954 us; speedup vs baseline: 1.0205x; 1.0072x over previous
//
#include <hip/hip_runtime.h>
#include <stdint.h>

#define B_ 8
#define L_ 4096
#define D_ 1024
#define M_ (B_*L_)        // 32768 rows
#define CHUNKS 128
#define TCH (L_/CHUNKS)   // 32

typedef float f32x4 __attribute__((ext_vector_type(4)));
typedef float f32x2 __attribute__((ext_vector_type(2)));
typedef short short8 __attribute__((ext_vector_type(8)));
typedef unsigned short ushort4v __attribute__((ext_vector_type(4)));

static __device__ __forceinline__ unsigned short f2bf(float f) {
  union { float f; unsigned u; } v; v.f = f;
  unsigned r = v.u + 0x7FFFu + ((v.u >> 16) & 1u);   // round-to-nearest-even
  return (unsigned short)(r >> 16);
}
static __device__ __forceinline__ float bf2f(unsigned short u) {
  union { unsigned u; float f; } v; v.u = ((unsigned)u) << 16; return v.f;
}

#define GLOAD16(g, l) \
  __builtin_amdgcn_global_load_lds((__attribute__((address_space(1))) const void*)(g), \
                                   (__attribute__((address_space(3))) void*)(l), 16, 0, 0)

// ---------------------------------------------------------------------------
// fp32 -> bf16 convert: x + W_f + W_i + W_o in ONE launch (dst contiguous).
// ---------------------------------------------------------------------------
__global__ __launch_bounds__(256)
void cvt_all(const float* __restrict__ x,  const float* __restrict__ w0,
             const float* __restrict__ w1, const float* __restrict__ w2,
             unsigned short* __restrict__ dst)
{
  const int xn8 = (M_ * D_) / 8;
  const int wn8 = (D_ * D_) / 8;
  int gid = blockIdx.x * 256 + threadIdx.x;
  const float* src;
  size_t soff;
  if (gid < xn8)                { src = x;  soff = (size_t)gid * 8; }
  else if (gid < xn8 + wn8)     { src = w0; soff = (size_t)(gid - xn8) * 8; }
  else if (gid < xn8 + 2 * wn8) { src = w1; soff = (size_t)(gid - xn8 - wn8) * 8; }
  else                          { src = w2; soff = (size_t)(gid - xn8 - 2 * wn8) * 8; }
  const f32x4* s = (const f32x4*)(src + soff);
  f32x4 v0 = s[0], v1 = s[1];
  union { short8 v; unsigned short u[8]; } w;
  w.u[0] = f2bf(v0[0]); w.u[1] = f2bf(v0[1]); w.u[2] = f2bf(v0[2]); w.u[3] = f2bf(v0[3]);
  w.u[4] = f2bf(v1[0]); w.u[5] = f2bf(v1[1]); w.u[6] = f2bf(v1[2]); w.u[7] = f2bf(v1[3]);
  *(short8*)(dst + (size_t)gid * 8) = w.v;
}

// ---------------------------------------------------------------------------
// 256x128 8-wave GEMM, 2 BLOCKS/CU (the m97/m114 implicit-overlap mechanism:
// when one block stalls at its vmcnt+barrier the co-resident block's waves
// feed the MFMA pipe — r8-r13's 256^2/1-block variants all plateaued 34-38%
// because nothing could issue during the block-wide stall).
// LDS 64 KB: A ring-3 (3 x 16KB chunks, 256 rows x 32 K) + B ring-2
// (2 x 8KB, 128 rows x 32 K) at +49152.  8 waves = 4x2 of 64x64.
// Per chunk c: {ld 4 A-frags + 4 B-frags; stgB(c+1); stgA(c+2); 16 MFMA;
// vmcnt(2) [drains A(c+1),B(c+1), leaves A(c+2)]; barrier}.
// MODE 0: stacked gates Bw=[W_f;W_i]; writes rem=lin*sig(zf+b), t=tanh(zi+b)
// MODE 1: y = h*W_o^T + b_o fp32.
// A-locality dispatch: 64 co-resident blocks/XCD = {GBM bm} x {NBN bn}.
// ---------------------------------------------------------------------------
template<int MODE>
__global__ __launch_bounds__(512, 4)
void gemm128(const unsigned short* __restrict__ A,
             const unsigned short* __restrict__ Bw,
             const float* __restrict__ bias0,
             const float* __restrict__ bias1,
             unsigned short* __restrict__ ob0,   // rem (MODE 0)
             unsigned short* __restrict__ ob1,   // t   (MODE 0)
             float* __restrict__ of)             // y   (MODE 1)
{
  __shared__ unsigned short lds[32768];   // 64 KB
  char* ldsb = (char*)lds;

  const int tid  = threadIdx.x;
  const int lane = tid & 63;
  const int wid  = tid >> 6;
  const int wm   = wid >> 1;          // 0..3 (64-row band)
  const int wn   = wid & 1;           // 0..1 (64-col band)
  const int frow = lane & 15, ks = lane >> 4;
  const int xsw  = (ks ^ ((frow >> 1) & 3)) << 4;

  constexpr int NBN = (MODE == 0) ? 16 : 8;   // 128-col tiles in N
  constexpr int GBM = 64 / NBN;               // bm panels per window (4 / 8)
  const int xcd   = blockIdx.x & 7;
  const int slot  = blockIdx.x >> 3;
  const int local = slot & 63;
  const int wrnd  = slot >> 6;
  const int bm = (xcd * 16 + wrnd * GBM + (local & (GBM - 1))) * 256;
  const int bn = (local / GBM) * 128;

  // staging sources (pre-swizzled k-slot; rule 21: LDS dest linear)
  const int r0  = tid >> 2;                              // 0..127
  const int scl = ((tid & 3) ^ ((r0 >> 1) & 3)) << 4;
  const char* pA = (const char*)A  + (size_t)(bm + r0) * 2048 + scl;
  const char* pB = (const char*)Bw + (size_t)(bn + r0) * 2048 + scl;
  const int dst16 = tid * 16;

  f32x4 acc[4][4] = {};
  short8 aq[4], bq[4];

  // A chunk: 256 rows x 32 K = 16 KB (2 gload16/thread)
  auto stgA = [&](int c, int sl) {
    const char* s = pA + c * 64;
    char* d = ldsb + sl * 16384 + dst16;
    GLOAD16(s,                      d);
    GLOAD16(s + (size_t)128 * 2048, d + 8192);
  };
  // B chunk: 128 rows x 32 K = 8 KB (1 gload16/thread)
  auto stgB = [&](int c, int sl) {
    const char* s = pB + c * 64;
    char* d = ldsb + 49152 + sl * 8192 + dst16;
    GLOAD16(s, d);
  };
  auto ldAB = [&](const char* LA, const char* LB) {
    const char* ab = LA + (wm * 64 + frow) * 64 + xsw;
    const char* bb = LB + (wn * 64 + frow) * 64 + xsw;
    aq[0] = *(const short8*)(ab);
    bq[0] = *(const short8*)(bb);
    bq[1] = *(const short8*)(bb + 1024);
    bq[2] = *(const short8*)(bb + 2048);
    bq[3] = *(const short8*)(bb + 3072);
    aq[1] = *(const short8*)(ab + 1024);
    aq[2] = *(const short8*)(ab + 2048);
    aq[3] = *(const short8*)(ab + 3072);
  };
  auto mfma16 = [&]() {
    #pragma unroll
    for (int i = 0; i < 4; ++i)
      #pragma unroll
      for (int j = 0; j < 4; ++j)
        acc[i][j] = __builtin_amdgcn_mfma_f32_16x16x32_bf16(aq[i], bq[j], acc[i][j], 0, 0, 0);
  };

#define BAR __builtin_amdgcn_s_barrier()
#define WAITV(N) asm volatile("s_waitcnt vmcnt(" #N ")" ::: "memory")
// chunk c: read A slot SA, B slot SB; stgB(c+1)->SGB, stgA(c+2)->SGA;
// 16 MFMA; wait WN (2 steady: drains A(c+1),B(c+1)); barrier.
#define DO_CH(c, SA, SB, SGA, SGB, STGA, STGB, WN)                            \
  {                                                                           \
    const char* LA = ldsb + (SA) * 16384;                                     \
    const char* LB = ldsb + 49152 + (SB) * 8192;                              \
    ldAB(LA, LB);                                                             \
    if (STGB) stgB((c) + 1, (SGB));                                           \
    if (STGA) stgA((c) + 2, (SGA));                                           \
    mfma16();                                                                 \
    WAITV(WN);                                                                \
    BAR;                                                                      \
  }
#define DO_CH_LAST(SA, SB)                                                    \
  {                                                                           \
    const char* LA = ldsb + (SA) * 16384;                                     \
    const char* LB = ldsb + 49152 + (SB) * 8192;                              \
    ldAB(LA, LB);                                                             \
    mfma16();                                                                 \
  }

  // prologue: A(0),B(0),A(1) -> 5 loads; vmcnt(2) leaves A(1) in flight
  stgA(0, 0);
  stgB(0, 0);
  stgA(1, 1);
  WAITV(2);
  BAR;

  DO_CH( 0, 0, 0, 2, 1, true, true, 2);
  DO_CH( 1, 1, 1, 0, 0, true, true, 2);
  DO_CH( 2, 2, 0, 1, 1, true, true, 2);
  DO_CH( 3, 0, 1, 2, 0, true, true, 2);
  DO_CH( 4, 1, 0, 0, 1, true, true, 2);
  DO_CH( 5, 2, 1, 1, 0, true, true, 2);
  DO_CH( 6, 0, 0, 2, 1, true, true, 2);
  DO_CH( 7, 1, 1, 0, 0, true, true, 2);
  DO_CH( 8, 2, 0, 1, 1, true, true, 2);
  DO_CH( 9, 0, 1, 2, 0, true, true, 2);
  DO_CH(10, 1, 0, 0, 1, true, true, 2);
  DO_CH(11, 2, 1, 1, 0, true, true, 2);
  DO_CH(12, 0, 0, 2, 1, true, true, 2);
  DO_CH(13, 1, 1, 0, 0, true, true, 2);
  DO_CH(14, 2, 0, 1, 1, true, true, 2);
  DO_CH(15, 0, 1, 2, 0, true, true, 2);
  DO_CH(16, 1, 0, 0, 1, true, true, 2);
  DO_CH(17, 2, 1, 1, 0, true, true, 2);
  DO_CH(18, 0, 0, 2, 1, true, true, 2);
  DO_CH(19, 1, 1, 0, 0, true, true, 2);
  DO_CH(20, 2, 0, 1, 1, true, true, 2);
  DO_CH(21, 0, 1, 2, 0, true, true, 2);
  DO_CH(22, 1, 0, 0, 1, true, true, 2);
  DO_CH(23, 2, 1, 1, 0, true, true, 2);
  DO_CH(24, 0, 0, 2, 1, true, true, 2);
  DO_CH(25, 1, 1, 0, 0, true, true, 2);
  DO_CH(26, 2, 0, 1, 1, true, true, 2);
  DO_CH(27, 0, 1, 2, 0, true, true, 2);
  DO_CH(28, 1, 0, 0, 1, true, true, 2);
  DO_CH(29, 2, 1, 1, 0, true, true, 2);   // last stgA: A(31)->slot 1
  DO_CH(30, 0, 0, 0, 1, false, true, 0);  // stgB(31)->slot 1; drain all
  DO_CH_LAST(1, 1);                       // chunk 31
#undef DO_CH
#undef DO_CH_LAST
#undef WAITV
#undef BAR

  // epilogue: C/D mapping col=lane&15, row=(lane>>4)*4+r
  if constexpr (MODE == 0) {
    const int plane = bn >> 10;                 // 0: rem, 1: tanh
    const int cb    = bn & 1023;
    unsigned short* ob = plane ? ob1 : ob0;
    const float* bs    = plane ? bias1 : bias0;
    float bv[4];
    #pragma unroll
    for (int j = 0; j < 4; ++j) bv[j] = bs[cb + wn * 64 + j * 16 + frow];
    #pragma unroll
    for (int i = 0; i < 4; ++i) {
      int row = bm + wm * 64 + i * 16 + ks * 4;
      #pragma unroll
      for (int j = 0; j < 4; ++j) {
        int col = cb + wn * 64 + j * 16 + frow;
        float lin = (float)col * (1.0f / 1023.0f);
        #pragma unroll
        for (int r = 0; r < 4; ++r) {
          float z = acc[i][j][r] + bv[j];
          float v;
          if (plane == 0) {
            v = lin / (1.0f + __expf(-z));             // rem (small, bf16-safe)
          } else {
            float e2 = __expf(2.0f * z);
            v = 1.0f - 2.0f / (e2 + 1.0f);             // tanh
          }
          ob[(size_t)(row + r) * D_ + col] = f2bf(v);
        }
      }
    }
  } else {
    float bv[4];
    #pragma unroll
    for (int j = 0; j < 4; ++j) bv[j] = bias0[bn + wn * 64 + j * 16 + frow];
    #pragma unroll
    for (int i = 0; i < 4; ++i) {
      int row = bm + wm * 64 + i * 16 + ks * 4;
      #pragma unroll
      for (int j = 0; j < 4; ++j) {
        int col = bn + wn * 64 + j * 16 + frow;
        #pragma unroll
        for (int r = 0; r < 4; ++r)
          of[(size_t)(row + r) * D_ + col] = acc[i][j][r] + bv[j];
      }
    }
  }
}

// ---------------------------------------------------------------------------
// Chunked parallel scan over precomputed (rem, t), 4 channels/thread.
// f = 1 - rem (fp32);  h_t = f*h_{t-1} + t*rem
// ---------------------------------------------------------------------------
__global__ __launch_bounds__(256)
void scan_partial_b(const unsigned short* __restrict__ rb,
                    const unsigned short* __restrict__ tb,
                    float* __restrict__ Ag, float* __restrict__ Ug)
{
  int blk = blockIdx.x;
  int b = blk >> 7, c = blk & (CHUNKS - 1);
  int e = threadIdx.x << 2;
  size_t base = ((size_t)b * L_ + (size_t)c * TCH) * D_ + e;
  f32x4 a = {1.f,1.f,1.f,1.f}, u = {0.f,0.f,0.f,0.f};
  for (int t = 0; t < TCH; ++t) {
    ushort4v r4 = *(const ushort4v*)(rb + base + (size_t)t * D_);
    ushort4v t4 = *(const ushort4v*)(tb + base + (size_t)t * D_);
    #pragma unroll
    for (int j = 0; j < 4; ++j) {
      float rem = bf2f(r4[j]);
      float f   = 1.0f - rem;
      float inp = bf2f(t4[j]) * rem;
      u[j] = fmaf(f, u[j], inp);
      a[j] *= f;
    }
  }
  size_t o = (size_t)(b * CHUNKS + c) * D_ + e;
  *(f32x4*)(Ag + o) = a;
  *(f32x4*)(Ug + o) = u;
}

__global__ __launch_bounds__(256)
void scan_carry(const float* __restrict__ Ag, const float* __restrict__ Ug,
                const float* __restrict__ hidden, float* __restrict__ Hin)
{
  int gid = blockIdx.x * 256 + threadIdx.x;  // B_*D_/4 threads
  int b = gid >> 8;
  int e = (gid & 255) << 2;
  f32x4 h = *(const f32x4*)(hidden + (size_t)b * D_ + e);
  for (int c = 0; c < CHUNKS; ++c) {
    size_t o = (size_t)(b * CHUNKS + c) * D_ + e;
    *(f32x4*)(Hin + o) = h;
    f32x4 A = *(const f32x4*)(Ag + o);
    f32x4 U = *(const f32x4*)(Ug + o);
    h = A * h + U;
  }
}

__global__ __launch_bounds__(256)
void scan_apply_b(const unsigned short* __restrict__ rb,
                  const unsigned short* __restrict__ tb,
                  const float* __restrict__ Hin,
                  float* __restrict__ hout, unsigned short* __restrict__ hb)
{
  int blk = blockIdx.x;
  int b = blk >> 7, c = blk & (CHUNKS - 1);
  int e = threadIdx.x << 2;
  size_t base = ((size_t)b * L_ + (size_t)c * TCH) * D_ + e;
  f32x4 h = *(const f32x4*)(Hin + (size_t)(b * CHUNKS + c) * D_ + e);
  for (int t = 0; t < TCH; ++t) {
    size_t o = base + (size_t)t * D_;
    ushort4v r4 = *(const ushort4v*)(rb + o);
    ushort4v t4 = *(const ushort4v*)(tb + o);
    #pragma unroll
    for (int j = 0; j < 4; ++j) {
      float rem = bf2f(r4[j]);
      float f   = 1.0f - rem;
      float inp = bf2f(t4[j]) * rem;
      h[j] = fmaf(f, h[j], inp);
    }
    *(f32x4*)(hout + o) = h;
    ushort4v p;
    p[0] = f2bf(h[0]); p[1] = f2bf(h[1]); p[2] = f2bf(h[2]); p[3] = f2bf(h[3]);
    *(ushort4v*)(hb + o) = p;
  }
}

// ---------------------------------------------------------------------------
// Slow fallback (fp32 in) — only if ws too small (never expected).
// ---------------------------------------------------------------------------
template<int MODE>
__global__ __launch_bounds__(256, 2)
void gemm_slow(const float* __restrict__ A, const float* __restrict__ B0,
               const float* __restrict__ B1, const float* __restrict__ bias0,
               const float* __restrict__ bias1, float* __restrict__ out0,
               float* __restrict__ out1)
{
  constexpr int BK = 32;
  __shared__ unsigned short As[128 * BK];
  __shared__ unsigned short Bs0[128 * BK];
  __shared__ unsigned short Bs1[(MODE == 0) ? (128 * BK) : 8];

  const int tid = threadIdx.x, lane = tid & 63, wave = tid >> 6;
  const int wr = wave >> 1, wc = wave & 1;
  const int bm = blockIdx.x * 128, bn = blockIdx.y * 128;
  f32x4 acc0[4][4] = {};
  f32x4 acc1[(MODE == 0) ? 4 : 1][(MODE == 0) ? 4 : 1] = {};
  const int frow = lane & 15, kslot = lane >> 4;
  const int xs = kslot ^ (frow & 3);

  auto stage = [&](const float* src, unsigned short* dst) {
    #pragma unroll
    for (int p = 0; p < 4; ++p) {
      int g = p * 256 + tid;
      int row = g >> 3, kq = (g & 7) << 2;
      f32x4 v = *(const f32x4*)(src + (size_t)row * D_ + kq);
      ushort4v w;
      w[0] = f2bf(v[0]); w[1] = f2bf(v[1]); w[2] = f2bf(v[2]); w[3] = f2bf(v[3]);
      int byte = kq << 1, slot = byte >> 4, sub = byte & 15;
      int off = row * 64 + ((slot ^ (row & 3)) << 4) + sub;
      *(ushort4v*)((char*)dst + off) = w;
    }
  };

  for (int k0 = 0; k0 < D_; k0 += BK) {
    stage(A + (size_t)bm * D_ + k0, As);
    stage(B0 + (size_t)bn * D_ + k0, Bs0);
    if constexpr (MODE == 0) stage(B1 + (size_t)bn * D_ + k0, Bs1);
    __syncthreads();
    short8 af[4], bf0[4], bf1[4];
    #pragma unroll
    for (int i = 0; i < 4; ++i) {
      int ar = wr * 64 + i * 16 + frow;
      af[i] = *(const short8*)((const char*)As + ar * 64 + (xs << 4));
      int br = wc * 64 + i * 16 + frow;
      bf0[i] = *(const short8*)((const char*)Bs0 + br * 64 + (xs << 4));
      if constexpr (MODE == 0)
        bf1[i] = *(const short8*)((const char*)Bs1 + br * 64 + (xs << 4));
    }
    #pragma unroll
    for (int i = 0; i < 4; ++i)
      #pragma unroll
      for (int j = 0; j < 4; ++j) {
        acc0[i][j] = __builtin_amdgcn_mfma_f32_16x16x32_bf16(af[i], bf0[j], acc0[i][j], 0, 0, 0);
        if constexpr (MODE == 0)
          acc1[i][j] = __builtin_amdgcn_mfma_f32_16x16x32_bf16(af[i], bf1[j], acc1[i][j], 0, 0, 0);
      }
    __syncthreads();
  }
  #pragma unroll
  for (int i = 0; i < 4; ++i)
    #pragma unroll
    for (int j = 0; j < 4; ++j)
      #pragma unroll
      for (int r = 0; r < 4; ++r) {
        int row = bm + wr * 64 + i * 16 + (lane >> 4) * 4 + r;
        int col = bn + wc * 64 + j * 16 + (lane & 15);
        size_t idx = (size_t)row * D_ + col;
        if constexpr (MODE == 0) {
          float zf = acc0[i][j][r] + bias0[col];
          float linv = (float)col * (1.0f / 1023.0f);
          float rem = linv / (1.0f + __expf(-zf));
          float zi = acc1[i][j][r] + bias1[col];
          float e2 = __expf(2.0f * zi);
          float th = 1.0f - 2.0f / (e2 + 1.0f);
          out0[idx] = 1.0f - rem;
          out1[idx] = th * rem;
        } else {
          out0[idx] = acc0[i][j][r] + bias0[col];
        }
      }
}

__global__ __launch_bounds__(256)
void scan_partial_f(const float* __restrict__ p0, const float* __restrict__ p1,
                    float* __restrict__ Ag, float* __restrict__ Ug)
{
  int blk = blockIdx.x;
  int b = blk / (CHUNKS * 2);
  int c = (blk >> 1) & (CHUNKS - 1);
  int e = ((blk & 1) << 9) + threadIdx.x * 2;
  size_t base = ((size_t)b * L_ + (size_t)c * TCH) * D_ + e;
  f32x2 a = {1.0f, 1.0f}, u = {0.0f, 0.0f};
  for (int t = 0; t < TCH; ++t) {
    f32x2 f = *(const f32x2*)(p0 + base + (size_t)t * D_);
    f32x2 i = *(const f32x2*)(p1 + base + (size_t)t * D_);
    u = f * u + i;
    a = a * f;
  }
  size_t o = (size_t)(b * CHUNKS + c) * D_ + e;
  *(f32x2*)(Ag + o) = a;
  *(f32x2*)(Ug + o) = u;
}

__global__ __launch_bounds__(256)
void scan_apply_f(const float* __restrict__ p0, float* __restrict__ p1_io,
                  const float* __restrict__ Hin)
{
  int blk = blockIdx.x;
  int b = blk / (CHUNKS * 2);
  int c = (blk >> 1) & (CHUNKS - 1);
  int e = ((blk & 1) << 9) + threadIdx.x * 2;
  size_t base = ((size_t)b * L_ + (size_t)c * TCH) * D_ + e;
  f32x2 h = *(const f32x2*)(Hin + (size_t)(b * CHUNKS + c) * D_ + e);
  for (int t = 0; t < TCH; ++t) {
    size_t o = base + (size_t)t * D_;
    f32x2 f = *(const f32x2*)(p0 + o);
    f32x2 i = *(const f32x2*)(p1_io + o);
    h = f * h + i;
    *(f32x2*)(p1_io + o) = h;
  }
}

// ---------------------------------------------------------------------------
extern "C" void kernel_launch(void* const* d_in, const int* in_sizes, int n_in,
                              void* d_out, int out_size, void* d_ws, size_t ws_size,
                              hipStream_t stream)
{
  const float* x      = (const float*)d_in[0];
  const float* hidden = (const float*)d_in[1];
  const float* W_f    = (const float*)d_in[2];
  const float* b_f    = (const float*)d_in[3];
  const float* W_i    = (const float*)d_in[4];
  const float* b_i    = (const float*)d_in[5];
  const float* W_o    = (const float*)d_in[6];
  const float* b_o    = (const float*)d_in[7];

  float* y = (float*)d_out;
  float* h = y + (size_t)M_ * D_;

  const size_t xb_elems = (size_t)M_ * D_;
  const size_t w_elems  = (size_t)D_ * D_;
  const size_t agg      = (size_t)B_ * CHUNKS * D_;
  const size_t need = (xb_elems * 3 + 3 * w_elems) * 2 + agg * 3 * 4;

  if (ws_size >= need) {
    unsigned short* xb  = (unsigned short*)d_ws;       // bf16 x, later bf16 h
    unsigned short* wfb = xb + xb_elems;               // [W_f;W_i] stacked
    unsigned short* wib = wfb + w_elems;
    unsigned short* wob = wib + w_elems;
    unsigned short* rbv = wob + w_elems;               // bf16 rem
    unsigned short* tbv = rbv + xb_elems;              // bf16 tanh
    float* Ag  = (float*)(tbv + xb_elems);
    float* Ug  = Ag + agg;
    float* Hin = Ug + agg;

    int cblk = (int)((xb_elems + 3 * w_elems) / 8 / 256);
    cvt_all<<<cblk, 256, 0, stream>>>(x, W_f, W_i, W_o, xb);

    gemm128<0><<<2048, 512, 0, stream>>>(xb, wfb, b_f, b_i, rbv, tbv, nullptr);

    int pblocks = B_ * CHUNKS;               // 1024
    scan_partial_b<<<pblocks, 256, 0, stream>>>(rbv, tbv, Ag, Ug);
    scan_carry<<<(B_ * D_ / 4) / 256, 256, 0, stream>>>(Ag, Ug, hidden, Hin);
    scan_apply_b<<<pblocks, 256, 0, stream>>>(rbv, tbv, Hin, h, xb);

    gemm128<1><<<1024, 512, 0, stream>>>(xb, wob, b_o, nullptr, nullptr, nullptr, y);
  } else {
    float* Ag  = (float*)d_ws;
    float* Ug  = Ag + agg;
    float* Hin = Ug + agg;
    dim3 gg(M_ / 128, D_ / 128);
    int pblocks = B_ * CHUNKS * 2;

    gemm_slow<0><<<gg, 256, 0, stream>>>(x, W_f, W_i, b_f, b_i, y, h);
    scan_partial_f<<<pblocks, 256, 0, stream>>>(y, h, Ag, Ug);
    scan_carry<<<(B_ * D_ / 4) / 256, 256, 0, stream>>>(Ag, Ug, hidden, Hin);
    scan_apply_f<<<pblocks, 256, 0, stream>>>(y, h, Hin);
    gemm_slow<1><<<gg, 256, 0, stream>>>(h, W_o, nullptr, b_o, nullptr, y, nullptr);
  }
}

// Round 15
// 390.272 us; speedup vs baseline: 1.0223x; 1.0017x over previous
//
#include <hip/hip_runtime.h>
#include <stdint.h>

#define B_ 8
#define L_ 4096
#define D_ 1024
#define M_ (B_*L_)        // 32768 rows
#define CHUNKS 128
#define TCH (L_/CHUNKS)   // 32

typedef float f32x4 __attribute__((ext_vector_type(4)));
typedef float f32x2 __attribute__((ext_vector_type(2)));
typedef short short8 __attribute__((ext_vector_type(8)));
typedef unsigned short ushort4v __attribute__((ext_vector_type(4)));

static __device__ __forceinline__ unsigned short f2bf(float f) {
  union { float f; unsigned u; } v; v.f = f;
  unsigned r = v.u + 0x7FFFu + ((v.u >> 16) & 1u);   // round-to-nearest-even
  return (unsigned short)(r >> 16);
}
static __device__ __forceinline__ float bf2f(unsigned short u) {
  union { unsigned u; float f; } v; v.u = ((unsigned)u) << 16; return v.f;
}

#define GLOAD16(g, l) \
  __builtin_amdgcn_global_load_lds((__attribute__((address_space(1))) const void*)(g), \
                                   (__attribute__((address_space(3))) void*)(l), 16, 0, 0)

// ---------------------------------------------------------------------------
// fp32 -> bf16 convert: x + W_f + W_i + W_o in ONE launch (dst contiguous).
// ---------------------------------------------------------------------------
__global__ __launch_bounds__(256)
void cvt_all(const float* __restrict__ x,  const float* __restrict__ w0,
             const float* __restrict__ w1, const float* __restrict__ w2,
             unsigned short* __restrict__ dst)
{
  const int xn8 = (M_ * D_) / 8;
  const int wn8 = (D_ * D_) / 8;
  int gid = blockIdx.x * 256 + threadIdx.x;
  const float* src;
  size_t soff;
  if (gid < xn8)                { src = x;  soff = (size_t)gid * 8; }
  else if (gid < xn8 + wn8)     { src = w0; soff = (size_t)(gid - xn8) * 8; }
  else if (gid < xn8 + 2 * wn8) { src = w1; soff = (size_t)(gid - xn8 - wn8) * 8; }
  else                          { src = w2; soff = (size_t)(gid - xn8 - 2 * wn8) * 8; }
  const f32x4* s = (const f32x4*)(src + soff);
  f32x4 v0 = s[0], v1 = s[1];
  union { short8 v; unsigned short u[8]; } w;
  w.u[0] = f2bf(v0[0]); w.u[1] = f2bf(v0[1]); w.u[2] = f2bf(v0[2]); w.u[3] = f2bf(v0[3]);
  w.u[4] = f2bf(v1[0]); w.u[5] = f2bf(v1[1]); w.u[6] = f2bf(v1[2]); w.u[7] = f2bf(v1[3]);
  *(short8*)(dst + (size_t)gid * 8) = w.v;
}

// ---------------------------------------------------------------------------
// 256x256 8-wave GEMM. Ring-5 chunk pipeline, stage-FIRST issue order:
//   chunk = 32 K-cols (16 KB); A ring-5 (80KB) + B ring-5 (80KB @ +81920).
//   Chunk c+4's global_load_lds issued at the TOP of chunk c (VMEM queue
//   entry ~100+cy earlier; ds_reads are independent and follow at once).
// Per chunk: {stgA/stgB(c+4); ldB4+ldA(ih0); 16 MFMA; ldA(ih1); 16 MFMA;
//   vmcnt(12) [drains exactly chunk c+1]; barrier}.  No setprio (m190).
// Conflict-free fragment reads (PMC=0); slot-XOR swizzle via pre-swizzled
// global source (rule 21).
// NOTE: 8 schedule variants (r8-r14) all plateau at 34-38% MfmaUtil — the
// documented m97-class plain-HIP K-loop ceiling (912 TF = 37%); the verified
// path beyond (m201 8-phase, 62%) did not reproduce from prose in 7 tries.
// MODE 0: stacked gates Bw=[W_f;W_i]; writes rem=lin*sig(zf+b), t=tanh(zi+b)
// MODE 1: y = h*W_o^T + b_o fp32.
// A-locality dispatch: 32 co-resident blocks/XCD = {GBM bm} x {all bn}.
// ---------------------------------------------------------------------------
template<int MODE>
__global__ __launch_bounds__(512, 2)
void gemm256(const unsigned short* __restrict__ A,
             const unsigned short* __restrict__ Bw,
             const float* __restrict__ bias0,
             const float* __restrict__ bias1,
             unsigned short* __restrict__ ob0,   // rem (MODE 0)
             unsigned short* __restrict__ ob1,   // t   (MODE 0)
             float* __restrict__ of)             // y   (MODE 1)
{
  __shared__ unsigned short lds[81920];   // 160 KB: A slots 0..4 | B slots at +81920
  char* ldsb = (char*)lds;

  const int tid  = threadIdx.x;
  const int lane = tid & 63;
  const int wid  = tid >> 6;
  const int wm   = wid >> 2;          // 0..1
  const int wn   = wid & 3;           // 0..3
  const int frow = lane & 15, ks = lane >> 4;
  const int xsw  = (ks ^ ((frow >> 1) & 3)) << 4;

  constexpr int NBN = (MODE == 0) ? 8 : 4;
  constexpr int GBM = 32 / NBN;
  const int xcd   = blockIdx.x & 7;
  const int slot  = blockIdx.x >> 3;
  const int local = slot & 31;
  const int wrnd  = slot >> 5;
  const int bm = (xcd * 16 + wrnd * GBM + (local & (GBM - 1))) * 256;
  const int bn = (local / GBM) * 256;

  const int r0  = tid >> 2;
  const int scl = ((tid & 3) ^ ((r0 >> 1) & 3)) << 4;   // pre-swizzled source slot
  const char* pA = (const char*)A  + (size_t)(bm + r0) * 2048 + scl;
  const char* pB = (const char*)Bw + (size_t)(bn + r0) * 2048 + scl;
  const int dst16 = tid * 16;

  f32x4 acc[8][4] = {};
  short8 aq[4], bq[4];

  // stage one 16KB chunk (32 K-cols) = 2 gload16/thread
  auto stgA = [&](int c, int sl) {
    const char* s = pA + c * 64;
    char* d = ldsb + sl * 16384 + dst16;
    GLOAD16(s,                      d);
    GLOAD16(s + (size_t)128 * 2048, d + 8192);
  };
  auto stgB = [&](int c, int sl) {
    const char* s = pB + c * 64;
    char* d = ldsb + 81920 + sl * 16384 + dst16;
    GLOAD16(s,                      d);
    GLOAD16(s + (size_t)128 * 2048, d + 8192);
  };
  auto ldAB4 = [&](const char* LA, const char* LB) {   // B frags + A ih0 rows
    const char* ab = LA + (wm * 128 + frow) * 64 + xsw;
    const char* bb = LB + (wn * 64 + frow) * 64 + xsw;
    aq[0] = *(const short8*)(ab);
    bq[0] = *(const short8*)(bb);
    bq[1] = *(const short8*)(bb + 1024);
    bq[2] = *(const short8*)(bb + 2048);
    bq[3] = *(const short8*)(bb + 3072);
    aq[1] = *(const short8*)(ab + 1024);
    aq[2] = *(const short8*)(ab + 2048);
    aq[3] = *(const short8*)(ab + 3072);
  };
  auto ldA4 = [&](const char* LA) {                    // A ih1 rows (+64)
    const char* ab = LA + (wm * 128 + 64 + frow) * 64 + xsw;
    aq[0] = *(const short8*)(ab);
    aq[1] = *(const short8*)(ab + 1024);
    aq[2] = *(const short8*)(ab + 2048);
    aq[3] = *(const short8*)(ab + 3072);
  };
  auto mfma16 = [&](int ih) {
    #pragma unroll
    for (int i2 = 0; i2 < 4; ++i2) {
      #pragma unroll
      for (int j = 0; j < 4; ++j)
        acc[ih * 4 + i2][j] =
          __builtin_amdgcn_mfma_f32_16x16x32_bf16(aq[i2], bq[j], acc[ih * 4 + i2][j], 0, 0, 0);
    }
  };

#define BAR __builtin_amdgcn_s_barrier()
#define WAITV(N) asm volatile("s_waitcnt vmcnt(" #N ")" ::: "memory")
// chunk c: stage chunk c+4 FIRST (earliest VMEM queue entry; WAR safe: slot
// SG's last reader finished at the barrier ending chunk c-1); then ds_reads
// of slot SL; MFMA; wait WN (drains chunk c+1); barrier.
#define DO_CH(c, SL, SG, STG, WN)                                             \
  {                                                                           \
    if (STG) { stgA((c) + 4, (SG)); stgB((c) + 4, (SG)); }                    \
    const char* LA = ldsb + (SL) * 16384;                                     \
    const char* LB = ldsb + 81920 + (SL) * 16384;                             \
    ldAB4(LA, LB);                                                            \
    mfma16(0);                                                                \
    ldA4(LA);                                                                 \
    mfma16(1);                                                                \
    WAITV(WN);                                                                \
    BAR;                                                                      \
  }
#define DO_CH_LAST(SL)                                                        \
  {                                                                           \
    const char* LA = ldsb + (SL) * 16384;                                     \
    const char* LB = ldsb + 81920 + (SL) * 16384;                             \
    ldAB4(LA, LB);                                                            \
    mfma16(0);                                                                \
    ldA4(LA);                                                                 \
    mfma16(1);                                                                \
  }

  // prologue: chunks 0..3 (A,B interleaved; oldest = chunk 0) -> 16 loads
  stgA(0, 0); stgB(0, 0);
  stgA(1, 1); stgB(1, 1);
  stgA(2, 2); stgB(2, 2);
  stgA(3, 3); stgB(3, 3);
  WAITV(12);                          // chunk 0 resident
  BAR;

  DO_CH( 0, 0, 4, true, 12);
  DO_CH( 1, 1, 0, true, 12);
  DO_CH( 2, 2, 1, true, 12);
  DO_CH( 3, 3, 2, true, 12);
  DO_CH( 4, 4, 3, true, 12);
  DO_CH( 5, 0, 4, true, 12);
  DO_CH( 6, 1, 0, true, 12);
  DO_CH( 7, 2, 1, true, 12);
  DO_CH( 8, 3, 2, true, 12);
  DO_CH( 9, 4, 3, true, 12);
  DO_CH(10, 0, 4, true, 12);
  DO_CH(11, 1, 0, true, 12);
  DO_CH(12, 2, 1, true, 12);
  DO_CH(13, 3, 2, true, 12);
  DO_CH(14, 4, 3, true, 12);
  DO_CH(15, 0, 4, true, 12);
  DO_CH(16, 1, 0, true, 12);
  DO_CH(17, 2, 1, true, 12);
  DO_CH(18, 3, 2, true, 12);
  DO_CH(19, 4, 3, true, 12);
  DO_CH(20, 0, 4, true, 12);
  DO_CH(21, 1, 0, true, 12);
  DO_CH(22, 2, 1, true, 12);
  DO_CH(23, 3, 2, true, 12);
  DO_CH(24, 4, 3, true, 12);
  DO_CH(25, 0, 4, true, 12);
  DO_CH(26, 1, 0, true, 12);
  DO_CH(27, 2, 1, true, 12);   // stages chunk 31 (last)
  DO_CH(28, 3, 0, false, 8);
  DO_CH(29, 4, 0, false, 4);
  DO_CH(30, 0, 0, false, 0);
  DO_CH_LAST(1);
#undef DO_CH
#undef DO_CH_LAST
#undef WAITV
#undef BAR

  // epilogue: C/D mapping col=lane&15, row=(lane>>4)*4+r
  if constexpr (MODE == 0) {
    const int plane = bn >> 10;                 // 0: rem, 1: tanh
    const int cb    = bn & 1023;
    unsigned short* ob = plane ? ob1 : ob0;
    const float* bs    = plane ? bias1 : bias0;
    float bv[4];
    #pragma unroll
    for (int j = 0; j < 4; ++j) bv[j] = bs[cb + wn * 64 + j * 16 + frow];
    #pragma unroll
    for (int ii = 0; ii < 8; ++ii) {
      int row = bm + wm * 128 + ii * 16 + ks * 4;
      #pragma unroll
      for (int j = 0; j < 4; ++j) {
        int col = cb + wn * 64 + j * 16 + frow;
        float lin = (float)col * (1.0f / 1023.0f);
        #pragma unroll
        for (int r = 0; r < 4; ++r) {
          float z = acc[ii][j][r] + bv[j];
          float v;
          if (plane == 0) {
            v = lin / (1.0f + __expf(-z));             // rem (small, bf16-safe)
          } else {
            float e2 = __expf(2.0f * z);
            v = 1.0f - 2.0f / (e2 + 1.0f);             // tanh
          }
          ob[(size_t)(row + r) * D_ + col] = f2bf(v);
        }
      }
    }
  } else {
    float bv[4];
    #pragma unroll
    for (int j = 0; j < 4; ++j) bv[j] = bias0[bn + wn * 64 + j * 16 + frow];
    #pragma unroll
    for (int ii = 0; ii < 8; ++ii) {
      int row = bm + wm * 128 + ii * 16 + ks * 4;
      #pragma unroll
      for (int j = 0; j < 4; ++j) {
        int col = bn + wn * 64 + j * 16 + frow;
        #pragma unroll
        for (int r = 0; r < 4; ++r)
          of[(size_t)(row + r) * D_ + col] = acc[ii][j][r] + bv[j];
      }
    }
  }
}

// ---------------------------------------------------------------------------
// Chunked parallel scan over precomputed (rem, t), 4 channels/thread.
// f = 1 - rem (fp32);  h_t = f*h_{t-1} + t*rem
// ---------------------------------------------------------------------------
__global__ __launch_bounds__(256)
void scan_partial_b(const unsigned short* __restrict__ rb,
                    const unsigned short* __restrict__ tb,
                    float* __restrict__ Ag, float* __restrict__ Ug)
{
  int blk = blockIdx.x;
  int b = blk >> 7, c = blk & (CHUNKS - 1);
  int e = threadIdx.x << 2;
  size_t base = ((size_t)b * L_ + (size_t)c * TCH) * D_ + e;
  f32x4 a = {1.f,1.f,1.f,1.f}, u = {0.f,0.f,0.f,0.f};
  for (int t = 0; t < TCH; ++t) {
    ushort4v r4 = *(const ushort4v*)(rb + base + (size_t)t * D_);
    ushort4v t4 = *(const ushort4v*)(tb + base + (size_t)t * D_);
    #pragma unroll
    for (int j = 0; j < 4; ++j) {
      float rem = bf2f(r4[j]);
      float f   = 1.0f - rem;
      float inp = bf2f(t4[j]) * rem;
      u[j] = fmaf(f, u[j], inp);
      a[j] *= f;
    }
  }
  size_t o = (size_t)(b * CHUNKS + c) * D_ + e;
  *(f32x4*)(Ag + o) = a;
  *(f32x4*)(Ug + o) = u;
}

__global__ __launch_bounds__(256)
void scan_carry(const float* __restrict__ Ag, const float* __restrict__ Ug,
                const float* __restrict__ hidden, float* __restrict__ Hin)
{
  int gid = blockIdx.x * 256 + threadIdx.x;  // B_*D_/4 threads
  int b = gid >> 8;
  int e = (gid & 255) << 2;
  f32x4 h = *(const f32x4*)(hidden + (size_t)b * D_ + e);
  for (int c = 0; c < CHUNKS; ++c) {
    size_t o = (size_t)(b * CHUNKS + c) * D_ + e;
    *(f32x4*)(Hin + o) = h;
    f32x4 A = *(const f32x4*)(Ag + o);
    f32x4 U = *(const f32x4*)(Ug + o);
    h = A * h + U;
  }
}

__global__ __launch_bounds__(256)
void scan_apply_b(const unsigned short* __restrict__ rb,
                  const unsigned short* __restrict__ tb,
                  const float* __restrict__ Hin,
                  float* __restrict__ hout, unsigned short* __restrict__ hb)
{
  int blk = blockIdx.x;
  int b = blk >> 7, c = blk & (CHUNKS - 1);
  int e = threadIdx.x << 2;
  size_t base = ((size_t)b * L_ + (size_t)c * TCH) * D_ + e;
  f32x4 h = *(const f32x4*)(Hin + (size_t)(b * CHUNKS + c) * D_ + e);
  for (int t = 0; t < TCH; ++t) {
    size_t o = base + (size_t)t * D_;
    ushort4v r4 = *(const ushort4v*)(rb + o);
    ushort4v t4 = *(const ushort4v*)(tb + o);
    #pragma unroll
    for (int j = 0; j < 4; ++j) {
      float rem = bf2f(r4[j]);
      float f   = 1.0f - rem;
      float inp = bf2f(t4[j]) * rem;
      h[j] = fmaf(f, h[j], inp);
    }
    *(f32x4*)(hout + o) = h;
    ushort4v p;
    p[0] = f2bf(h[0]); p[1] = f2bf(h[1]); p[2] = f2bf(h[2]); p[3] = f2bf(h[3]);
    *(ushort4v*)(hb + o) = p;
  }
}

// ---------------------------------------------------------------------------
// Slow fallback (fp32 in) — only if ws too small (never expected).
// ---------------------------------------------------------------------------
template<int MODE>
__global__ __launch_bounds__(256, 2)
void gemm_slow(const float* __restrict__ A, const float* __restrict__ B0,
               const float* __restrict__ B1, const float* __restrict__ bias0,
               const float* __restrict__ bias1, float* __restrict__ out0,
               float* __restrict__ out1)
{
  constexpr int BK = 32;
  __shared__ unsigned short As[128 * BK];
  __shared__ unsigned short Bs0[128 * BK];
  __shared__ unsigned short Bs1[(MODE == 0) ? (128 * BK) : 8];

  const int tid = threadIdx.x, lane = tid & 63, wave = tid >> 6;
  const int wr = wave >> 1, wc = wave & 1;
  const int bm = blockIdx.x * 128, bn = blockIdx.y * 128;
  f32x4 acc0[4][4] = {};
  f32x4 acc1[(MODE == 0) ? 4 : 1][(MODE == 0) ? 4 : 1] = {};
  const int frow = lane & 15, kslot = lane >> 4;
  const int xs = kslot ^ (frow & 3);

  auto stage = [&](const float* src, unsigned short* dst) {
    #pragma unroll
    for (int p = 0; p < 4; ++p) {
      int g = p * 256 + tid;
      int row = g >> 3, kq = (g & 7) << 2;
      f32x4 v = *(const f32x4*)(src + (size_t)row * D_ + kq);
      ushort4v w;
      w[0] = f2bf(v[0]); w[1] = f2bf(v[1]); w[2] = f2bf(v[2]); w[3] = f2bf(v[3]);
      int byte = kq << 1, slot = byte >> 4, sub = byte & 15;
      int off = row * 64 + ((slot ^ (row & 3)) << 4) + sub;
      *(ushort4v*)((char*)dst + off) = w;
    }
  };

  for (int k0 = 0; k0 < D_; k0 += BK) {
    stage(A + (size_t)bm * D_ + k0, As);
    stage(B0 + (size_t)bn * D_ + k0, Bs0);
    if constexpr (MODE == 0) stage(B1 + (size_t)bn * D_ + k0, Bs1);
    __syncthreads();
    short8 af[4], bf0[4], bf1[4];
    #pragma unroll
    for (int i = 0; i < 4; ++i) {
      int ar = wr * 64 + i * 16 + frow;
      af[i] = *(const short8*)((const char*)As + ar * 64 + (xs << 4));
      int br = wc * 64 + i * 16 + frow;
      bf0[i] = *(const short8*)((const char*)Bs0 + br * 64 + (xs << 4));
      if constexpr (MODE == 0)
        bf1[i] = *(const short8*)((const char*)Bs1 + br * 64 + (xs << 4));
    }
    #pragma unroll
    for (int i = 0; i < 4; ++i)
      #pragma unroll
      for (int j = 0; j < 4; ++j) {
        acc0[i][j] = __builtin_amdgcn_mfma_f32_16x16x32_bf16(af[i], bf0[j], acc0[i][j], 0, 0, 0);
        if constexpr (MODE == 0)
          acc1[i][j] = __builtin_amdgcn_mfma_f32_16x16x32_bf16(af[i], bf1[j], acc1[i][j], 0, 0, 0);
      }
    __syncthreads();
  }
  #pragma unroll
  for (int i = 0; i < 4; ++i)
    #pragma unroll
    for (int j = 0; j < 4; ++j)
      #pragma unroll
      for (int r = 0; r < 4; ++r) {
        int row = bm + wr * 64 + i * 16 + (lane >> 4) * 4 + r;
        int col = bn + wc * 64 + j * 16 + (lane & 15);
        size_t idx = (size_t)row * D_ + col;
        if constexpr (MODE == 0) {
          float zf = acc0[i][j][r] + bias0[col];
          float linv = (float)col * (1.0f / 1023.0f);
          float rem = linv / (1.0f + __expf(-zf));
          float zi = acc1[i][j][r] + bias1[col];
          float e2 = __expf(2.0f * zi);
          float th = 1.0f - 2.0f / (e2 + 1.0f);
          out0[idx] = 1.0f - rem;
          out1[idx] = th * rem;
        } else {
          out0[idx] = acc0[i][j][r] + bias0[col];
        }
      }
}

__global__ __launch_bounds__(256)
void scan_partial_f(const float* __restrict__ p0, const float* __restrict__ p1,
                    float* __restrict__ Ag, float* __restrict__ Ug)
{
  int blk = blockIdx.x;
  int b = blk / (CHUNKS * 2);
  int c = (blk >> 1) & (CHUNKS - 1);
  int e = ((blk & 1) << 9) + threadIdx.x * 2;
  size_t base = ((size_t)b * L_ + (size_t)c * TCH) * D_ + e;
  f32x2 a = {1.0f, 1.0f}, u = {0.0f, 0.0f};
  for (int t = 0; t < TCH; ++t) {
    f32x2 f = *(const f32x2*)(p0 + base + (size_t)t * D_);
    f32x2 i = *(const f32x2*)(p1 + base + (size_t)t * D_);
    u = f * u + i;
    a = a * f;
  }
  size_t o = (size_t)(b * CHUNKS + c) * D_ + e;
  *(f32x2*)(Ag + o) = a;
  *(f32x2*)(Ug + o) = u;
}

__global__ __launch_bounds__(256)
void scan_apply_f(const float* __restrict__ p0, float* __restrict__ p1_io,
                  const float* __restrict__ Hin)
{
  int blk = blockIdx.x;
  int b = blk / (CHUNKS * 2);
  int c = (blk >> 1) & (CHUNKS - 1);
  int e = ((blk & 1) << 9) + threadIdx.x * 2;
  size_t base = ((size_t)b * L_ + (size_t)c * TCH) * D_ + e;
  f32x2 h = *(const f32x2*)(Hin + (size_t)(b * CHUNKS + c) * D_ + e);
  for (int t = 0; t < TCH; ++t) {
    size_t o = base + (size_t)t * D_;
    f32x2 f = *(const f32x2*)(p0 + o);
    f32x2 i = *(const f32x2*)(p1_io + o);
    h = f * h + i;
    *(f32x2*)(p1_io + o) = h;
  }
}

// ---------------------------------------------------------------------------
extern "C" void kernel_launch(void* const* d_in, const int* in_sizes, int n_in,
                              void* d_out, int out_size, void* d_ws, size_t ws_size,
                              hipStream_t stream)
{
  const float* x      = (const float*)d_in[0];
  const float* hidden = (const float*)d_in[1];
  const float* W_f    = (const float*)d_in[2];
  const float* b_f    = (const float*)d_in[3];
  const float* W_i    = (const float*)d_in[4];
  const float* b_i    = (const float*)d_in[5];
  const float* W_o    = (const float*)d_in[6];
  const float* b_o    = (const float*)d_in[7];

  float* y = (float*)d_out;
  float* h = y + (size_t)M_ * D_;

  const size_t xb_elems = (size_t)M_ * D_;
  const size_t w_elems  = (size_t)D_ * D_;
  const size_t agg      = (size_t)B_ * CHUNKS * D_;
  const size_t need = (xb_elems * 3 + 3 * w_elems) * 2 + agg * 3 * 4;

  if (ws_size >= need) {
    unsigned short* xb  = (unsigned short*)d_ws;       // bf16 x, later bf16 h
    unsigned short* wfb = xb + xb_elems;               // [W_f;W_i] stacked
    unsigned short* wib = wfb + w_elems;
    unsigned short* wob = wib + w_elems;
    unsigned short* rbv = wob + w_elems;               // bf16 rem
    unsigned short* tbv = rbv + xb_elems;              // bf16 tanh
    float* Ag  = (float*)(tbv + xb_elems);
    float* Ug  = Ag + agg;
    float* Hin = Ug + agg;

    int cblk = (int)((xb_elems + 3 * w_elems) / 8 / 256);
    cvt_all<<<cblk, 256, 0, stream>>>(x, W_f, W_i, W_o, xb);

    gemm256<0><<<1024, 512, 0, stream>>>(xb, wfb, b_f, b_i, rbv, tbv, nullptr);

    int pblocks = B_ * CHUNKS;               // 1024
    scan_partial_b<<<pblocks, 256, 0, stream>>>(rbv, tbv, Ag, Ug);
    scan_carry<<<(B_ * D_ / 4) / 256, 256, 0, stream>>>(Ag, Ug, hidden, Hin);
    scan_apply_b<<<pblocks, 256, 0, stream>>>(rbv, tbv, Hin, h, xb);

    gemm256<1><<<512, 512, 0, stream>>>(xb, wob, b_o, nullptr, nullptr, nullptr, y);
  } else {
    float* Ag  = (float*)d_ws;
    float* Ug  = Ag + agg;
    float* Hin = Ug + agg;
    dim3 gg(M_ / 128, D_ / 128);
    int pblocks = B_ * CHUNKS * 2;

    gemm_slow<0><<<gg, 256, 0, stream>>>(x, W_f, W_i, b_f, b_i, y, h);
    scan_partial_f<<<pblocks, 256, 0, stream>>>(y, h, Ag, Ug);
    scan_carry<<<(B_ * D_ / 4) / 256, 256, 0, stream>>>(Ag, Ug, hidden, Hin);
    scan_apply_f<<<pblocks, 256, 0, stream>>>(y, h, Hin);
    gemm_slow<1><<<gg, 256, 0, stream>>>(h, W_o, nullptr, b_o, nullptr, y, nullptr);
  }
}